// Round 2
// baseline (2175.395 us; speedup 1.0000x reference)
//
#include <hip/hip_runtime.h>

// ---------------------------------------------------------------------------
// AxialAttention (relative-position attention + 3 training-mode BatchNorms)
// B=4 L=1024 C=512 DK=512 DV=1024 H=8 DKH=64 DVH=128, rel table R=509
//
// Pipeline (all fp32; correctness-first baseline):
//   K1 gemm_qkv    : qkv = x @ W_qkv                      [4096 x 2048]
//   K2 colstats    : per-channel sum/sumsq of qkv (atomics)
//   K3 fold_qkv    : scale/shift per channel (BN fold)
//   K4 attn<0>     : recompute sims (content / q-rpe / k-rpe), accumulate
//                    per-(s,h) sum/sumsq (BN-sim stats)
//   K5 fold_sim    : a[s,h], c[h]  (logits = a0*s0+a1*s1+a2*s2+c)
//   K6 attn<1>     : sims -> logits -> online softmax (defer-max THR=8)
//                    -> PV content + rel-PV via 509-bin Wr trick -> retrieved
//   K7 outstats    : per-(s,h,d) sum/sumsq of retrieved
//   K8 final       : out BN + sum over s + transpose to [B,L,DV]
// ---------------------------------------------------------------------------

#define EPSN 1e-5f

// ---- workspace layout (float offsets) ----
#define WS_QKV      0ul                         // 4096*2048 = 8388608
#define WS_STATS    8388608ul                   // zeroed region start
#define WS_COLSUM   (WS_STATS)                  // 2048
#define WS_COLSQ    (WS_STATS + 2048)           // 2048
#define WS_SIMSUM   (WS_STATS + 4096)           // 24
#define WS_SIMSQ    (WS_STATS + 4120)           // 24
#define WS_OUTSUM   (WS_STATS + 4144)           // 2048
#define WS_OUTSQ    (WS_STATS + 6192)           // 2048
#define WS_STATS_N  8240ul
#define WS_FOLD     (WS_STATS + WS_STATS_N)
#define WS_QSCALE   (WS_FOLD)                   // 2048
#define WS_QSHIFT   (WS_FOLD + 2048)            // 2048
#define WS_SIMA     (WS_FOLD + 4096)            // 24
#define WS_SIMC     (WS_FOLD + 4120)            // 8
#define WS_RET      (WS_FOLD + 4128)            // 2*4*8*1024*128 = 8388608
#define WS_TOTAL_FLOATS (WS_RET + 8388608ul)    // 16,789,584 floats ~= 67.2 MB

__device__ __forceinline__ unsigned short f2bf(float x) {
    union { float f; unsigned int u; } c; c.f = x;
    unsigned int u = c.u + 0x7fffu + ((c.u >> 16) & 1u);   // RNE
    return (unsigned short)(u >> 16);
}
__device__ __forceinline__ float bf2f(unsigned short x) {
    union { unsigned int u; float f; } c; c.u = ((unsigned int)x) << 16;
    return c.f;
}

// ---------------------------------------------------------------------------
// K1: qkv = x[4096,512] @ W[512,2048], fp32 tiled GEMM (64x64 tile, 4x4/thread)
// ---------------------------------------------------------------------------
__global__ __launch_bounds__(256) void k_gemm_qkv(const float* __restrict__ x,
                                                  const float* __restrict__ w,
                                                  float* __restrict__ qkv) {
    __shared__ float As[16][68];   // As[k][row]  (transposed A tile)
    __shared__ float Bs[16][68];   // Bs[k][col]
    const int t  = threadIdx.x;
    const int tx = t & 15;         // col group (4 cols)
    const int ty = t >> 4;         // row group (4 rows)
    const int n0 = blockIdx.x * 64;
    const int r0 = blockIdx.y * 64;
    const int ar = t >> 2, akv = t & 3;    // A staging: row, k-float4
    const int bk = t >> 4, bn = t & 15;    // B staging: k, col-float4
    float acc[4][4];
    #pragma unroll
    for (int i = 0; i < 4; ++i)
        #pragma unroll
        for (int j = 0; j < 4; ++j) acc[i][j] = 0.f;

    for (int k0 = 0; k0 < 512; k0 += 16) {
        __syncthreads();
        float4 av = *(const float4*)(x + (size_t)(r0 + ar) * 512 + k0 + akv * 4);
        As[akv*4+0][ar] = av.x; As[akv*4+1][ar] = av.y;
        As[akv*4+2][ar] = av.z; As[akv*4+3][ar] = av.w;
        float4 bv = *(const float4*)(w + (size_t)(k0 + bk) * 2048 + n0 + bn * 4);
        *(float4*)&Bs[bk][bn*4] = bv;
        __syncthreads();
        #pragma unroll
        for (int kk = 0; kk < 16; ++kk) {
            float4 a = *(const float4*)&As[kk][ty*4];
            float4 b = *(const float4*)&Bs[kk][tx*4];
            acc[0][0] += a.x*b.x; acc[0][1] += a.x*b.y; acc[0][2] += a.x*b.z; acc[0][3] += a.x*b.w;
            acc[1][0] += a.y*b.x; acc[1][1] += a.y*b.y; acc[1][2] += a.y*b.z; acc[1][3] += a.y*b.w;
            acc[2][0] += a.z*b.x; acc[2][1] += a.z*b.y; acc[2][2] += a.z*b.z; acc[2][3] += a.z*b.w;
            acc[3][0] += a.w*b.x; acc[3][1] += a.w*b.y; acc[3][2] += a.w*b.z; acc[3][3] += a.w*b.w;
        }
    }
    #pragma unroll
    for (int i = 0; i < 4; ++i) {
        float4 o = make_float4(acc[i][0], acc[i][1], acc[i][2], acc[i][3]);
        *(float4*)(qkv + (size_t)(r0 + ty*4 + i) * 2048 + n0 + tx*4) = o;
    }
}

// ---------------------------------------------------------------------------
// K2: per-channel sum/sumsq of row-major [4096, 2048] (atomics per chunk)
// ---------------------------------------------------------------------------
__global__ __launch_bounds__(256) void k_colstats(const float* __restrict__ src,
                                                  float* __restrict__ sum,
                                                  float* __restrict__ sq) {
    const int ch = blockIdx.x * 256 + threadIdx.x;
    const int r0 = blockIdx.y * 256;
    float s = 0.f, q = 0.f;
    for (int r = 0; r < 256; ++r) {
        float v = src[(size_t)(r0 + r) * 2048 + ch];
        s += v; q += v * v;
    }
    atomicAdd(&sum[ch], s);
    atomicAdd(&sq[ch], q);
}

// K3: fold qkv BN into per-channel scale/shift
__global__ __launch_bounds__(256) void k_fold_qkv(const float* __restrict__ sum,
                                                  const float* __restrict__ sq,
                                                  const float* __restrict__ gamma,
                                                  const float* __restrict__ beta,
                                                  float* __restrict__ scale,
                                                  float* __restrict__ shift) {
    const int ch = blockIdx.x * 256 + threadIdx.x;
    float m = sum[ch] * (1.f / 4096.f);
    float v = sq[ch] * (1.f / 4096.f) - m * m;
    float sc = gamma[ch] * rsqrtf(v + EPSN);
    scale[ch] = sc;
    shift[ch] = beta[ch] - sc * m;
}

// K5: fold sim BN: a[s,h] = gamma*rsqrt(var+eps), c[h] = sum_s(beta - a*mean)
__global__ void k_fold_sim(const float* __restrict__ simsum,
                           const float* __restrict__ simsq,
                           const float* __restrict__ gamma,
                           const float* __restrict__ beta,
                           float* __restrict__ a_out,
                           float* __restrict__ c_out) {
    __shared__ float part[24];
    const int t = threadIdx.x;
    const float inv = 1.f / (4.f * 1024.f * 1024.f);
    if (t < 24) {
        float m = simsum[t] * inv;
        float v = simsq[t] * inv - m * m;
        float a = gamma[t] * rsqrtf(v + EPSN);
        a_out[t] = a;
        part[t] = beta[t] - a * m;
    }
    __syncthreads();
    if (t < 8) c_out[t] = part[t] + part[8 + t] + part[16 + t];
}

// ---------------------------------------------------------------------------
// K4/K6: the attention kernel. One block = (b, h, 32-row l-tile), 256 thr.
// Wave w owns rows w*8..w*8+7 for the whole block (softmax state in regs).
// MODE 0: sims only -> per-(s,h) sum/sumsq atomics.
// MODE 1: full softmax + PV-content + Wr-binned rel-PV -> retrieved.
// LDS (floats): Q[32][68] K[64][68] QR[95][68] KR[95][68]
//               (MODE1) V[64][129] ws[32][68] Wr bf16[32][512]
// ---------------------------------------------------------------------------
#define oQ  0
#define oK  2176
#define oQR 6528
#define oKR 12988
#define oV  19448
#define oWs 27704
#define oWr 29880
#define SMEM0_BYTES ((19448 + 32) * 4)       // 77,920  (2 blocks/CU)
#define SMEM1_BYTES ((29880 + 8192) * 4)     // 152,288 (1 block/CU)

template <int MODE>
__global__ __launch_bounds__(256) void k_attn(
        const float* __restrict__ qkv,
        const float* __restrict__ qscale, const float* __restrict__ qshift,
        const float* __restrict__ eq, const float* __restrict__ ek,
        const float* __restrict__ ev,
        const float* __restrict__ sim_a, const float* __restrict__ sim_c,
        float* __restrict__ simsum, float* __restrict__ simsq,
        float* __restrict__ ret) {
    extern __shared__ float sm[];
    const int t = threadIdx.x;
    const int lane = t & 63, wid = t >> 6;
    const int blk = blockIdx.x;
    const int lt = blk & 31;
    const int h  = (blk >> 5) & 7;
    const int b  = blk >> 8;
    const int l0 = lt * 32;
    const size_t bbase = (size_t)b * 1024 * 2048;

    // ---- stage Q tile [32][64], BN-folded ----
    #pragma unroll
    for (int i = 0; i < 2; ++i) {
        int ff = t + i * 256;            // 0..511
        int row = ff >> 4, dv = ff & 15;
        int ch = h * 64 + dv * 4;
        float4 v   = *(const float4*)(qkv + bbase + (size_t)(l0 + row) * 2048 + ch);
        float4 sc4 = *(const float4*)(qscale + ch);
        float4 sh4 = *(const float4*)(qshift + ch);
        float* dst = &sm[oQ + row * 68 + dv * 4];
        dst[0] = v.x * sc4.x + sh4.x; dst[1] = v.y * sc4.y + sh4.y;
        dst[2] = v.z * sc4.z + sh4.z; dst[3] = v.w * sc4.w + sh4.w;
    }

    float Mrow[8], Drow[8], e0r[8], e1r[8], accc[8][2];
    if (MODE) {
        #pragma unroll
        for (int r = 0; r < 8; ++r) {
            Mrow[r] = -1e30f; Drow[r] = 0.f; e0r[r] = 0.f; e1r[r] = 0.f;
            accc[r][0] = 0.f; accc[r][1] = 0.f;
        }
        unsigned int* wz = (unsigned int*)&sm[oWr];
        for (int i = t; i < 8192; i += 256) wz[i] = 0u;    // zero Wr (bf16 pairs)
    }
    float s0 = 0, q0 = 0, s1 = 0, q1 = 0, s2 = 0, q2 = 0;
    float a0c = 0, a1c = 0, a2c = 0, cc = 0;
    if (MODE) {
        a0c = sim_a[h]; a1c = sim_a[8 + h]; a2c = sim_a[16 + h]; cc = sim_c[h];
    }

    for (int mt = 0; mt < 16; ++mt) {
        const int m0 = mt * 64;
        __syncthreads();
        // ---- stage K [64][64] ----
        #pragma unroll
        for (int i = 0; i < 4; ++i) {
            int ff = t + i * 256;          // 0..1023
            int m = ff >> 4, dv = ff & 15;
            int ch = 512 + h * 64 + dv * 4;
            float4 v   = *(const float4*)(qkv + bbase + (size_t)(m0 + m) * 2048 + ch);
            float4 sc4 = *(const float4*)(qscale + ch);
            float4 sh4 = *(const float4*)(qshift + ch);
            float* dst = &sm[oK + m * 68 + dv * 4];
            dst[0] = v.x * sc4.x + sh4.x; dst[1] = v.y * sc4.y + sh4.y;
            dst[2] = v.z * sc4.z + sh4.z; dst[3] = v.w * sc4.w + sh4.w;
        }
        // ---- stage q_rpe / k_rpe rows: 95 rows x 64, clamped gather ----
        {
            const int rmin = m0 - l0 + 223;   // m0 - (l0+31) + 254
            for (int ff = t; ff < 1520; ff += 256) {
                int j = ff >> 4, dv = ff & 15;
                int r = rmin + j; r = r < 0 ? 0 : (r > 508 ? 508 : r);
                float4 v1 = *(const float4*)(eq + (size_t)r * 64 + dv * 4);
                float* d1 = &sm[oQR + j * 68 + dv * 4];
                d1[0] = v1.x; d1[1] = v1.y; d1[2] = v1.z; d1[3] = v1.w;
                float4 v2 = *(const float4*)(ek + (size_t)r * 64 + dv * 4);
                float* d2 = &sm[oKR + j * 68 + dv * 4];
                d2[0] = v2.x; d2[1] = v2.y; d2[2] = v2.z; d2[3] = v2.w;
            }
        }
        if (MODE) {
            // ---- stage V [64][128] ----
            #pragma unroll
            for (int i = 0; i < 8; ++i) {
                int ff = t + i * 256;       // 0..2047
                int m = ff >> 5, dv = ff & 31;
                int ch = 1024 + h * 128 + dv * 4;
                float4 v   = *(const float4*)(qkv + bbase + (size_t)(m0 + m) * 2048 + ch);
                float4 sc4 = *(const float4*)(qscale + ch);
                float4 sh4 = *(const float4*)(qshift + ch);
                float* dst = &sm[oV + m * 129 + dv * 4];
                dst[0] = v.x * sc4.x + sh4.x; dst[1] = v.y * sc4.y + sh4.y;
                dst[2] = v.z * sc4.z + sh4.z; dst[3] = v.w * sc4.w + sh4.w;
            }
        }
        __syncthreads();

        // ---- sims (+ softmax in MODE1): lanes over m ----
        #pragma unroll
        for (int rr = 0; rr < 8; ++rr) {
            const int lrow = wid * 8 + rr;
            const int jj = lane - lrow + 31;
            const float* qp  = &sm[oQ  + lrow * 68];
            const float* kp  = &sm[oK  + lane * 68];
            const float* qrp = &sm[oQR + jj * 68];
            const float* krp = &sm[oKR + jj * 68];
            float A0 = 0.f, A1 = 0.f, A2 = 0.f;
            #pragma unroll 4
            for (int d4 = 0; d4 < 16; ++d4) {
                float4 q  = *(const float4*)(qp  + d4 * 4);
                float4 k  = *(const float4*)(kp  + d4 * 4);
                float4 qr = *(const float4*)(qrp + d4 * 4);
                float4 kr = *(const float4*)(krp + d4 * 4);
                A0 += q.x*k.x  + q.y*k.y  + q.z*k.z  + q.w*k.w;
                A1 += q.x*qr.x + q.y*qr.y + q.z*qr.z + q.w*qr.w;
                A2 += k.x*kr.x + k.y*kr.y + k.z*kr.z + k.w*kr.w;
            }
            if (MODE == 0) {
                s0 += A0; q0 += A0 * A0;
                s1 += A1; q1 += A1 * A1;
                s2 += A2; q2 += A2 * A2;
            } else {
                float logit = cc + a0c * A0 + a1c * A1 + a2c * A2;
                float tm = logit;
                #pragma unroll
                for (int off = 32; off; off >>= 1) tm = fmaxf(tm, __shfl_xor(tm, off));
                float M = Mrow[rr];
                if (tm > M + 8.f) {               // defer-max: rescale rarely
                    float scl = __expf(M - tm);
                    Drow[rr] *= scl; accc[rr][0] *= scl; accc[rr][1] *= scl;
                    e0r[rr] *= scl; e1r[rr] *= scl;
                    unsigned short* wrp = (unsigned short*)&sm[oWr] + lrow * 512;
                    #pragma unroll
                    for (int ii = 0; ii < 8; ++ii) {
                        int idx = lane + ii * 64;
                        wrp[idx] = f2bf(bf2f(wrp[idx]) * scl);
                    }
                    M = tm; Mrow[rr] = tm;
                }
                float wv = __expf(logit - M);
                float ts = wv;
                #pragma unroll
                for (int off = 32; off; off >>= 1) ts += __shfl_xor(ts, off);
                Drow[rr] += ts;
                const int l_g = l0 + lrow;
                const int r_raw = m0 + lane - l_g + 254;
                const bool lo = r_raw <= 0, hi = r_raw >= 508;
                if (m0 - l_g + 254 <= 0) {
                    float ew = lo ? wv : 0.f;
                    #pragma unroll
                    for (int off = 32; off; off >>= 1) ew += __shfl_xor(ew, off);
                    e0r[rr] += ew;
                }
                if (m0 + 63 - l_g + 254 >= 508) {
                    float ew = hi ? wv : 0.f;
                    #pragma unroll
                    for (int off = 32; off; off >>= 1) ew += __shfl_xor(ew, off);
                    e1r[rr] += ew;
                }
                if (!lo && !hi)
                    ((unsigned short*)&sm[oWr])[lrow * 512 + r_raw] = f2bf(wv);
                sm[oWs + lrow * 68 + lane] = wv;
            }
        }

        if (MODE) {
            // ---- PV content: lanes over d, reuse V rows across 8 rows ----
            #pragma unroll 2
            for (int m4 = 0; m4 < 16; ++m4) {
                float4 wv4[8];
                #pragma unroll
                for (int rr = 0; rr < 8; ++rr)
                    wv4[rr] = *(const float4*)&sm[oWs + (wid * 8 + rr) * 68 + m4 * 4];
                #pragma unroll
                for (int mm = 0; mm < 4; ++mm) {
                    int m = m4 * 4 + mm;
                    float v0 = sm[oV + m * 129 + lane];
                    float v1 = sm[oV + m * 129 + 64 + lane];
                    #pragma unroll
                    for (int rr = 0; rr < 8; ++rr) {
                        float w = mm == 0 ? wv4[rr].x : mm == 1 ? wv4[rr].y
                                : mm == 2 ? wv4[rr].z : wv4[rr].w;
                        accc[rr][0] += w * v0;
                        accc[rr][1] += w * v1;
                    }
                }
            }
        }
    }

    if (MODE == 0) {
        #pragma unroll
        for (int off = 32; off; off >>= 1) {
            s0 += __shfl_xor(s0, off); q0 += __shfl_xor(q0, off);
            s1 += __shfl_xor(s1, off); q1 += __shfl_xor(q1, off);
            s2 += __shfl_xor(s2, off); q2 += __shfl_xor(q2, off);
        }
        __syncthreads();
        float* red = &sm[oV];     // reuse (MODE0 smem ends at oV+32)
        if (lane == 0) {
            red[wid * 6 + 0] = s0; red[wid * 6 + 1] = q0;
            red[wid * 6 + 2] = s1; red[wid * 6 + 3] = q1;
            red[wid * 6 + 4] = s2; red[wid * 6 + 5] = q2;
        }
        __syncthreads();
        if (t == 0) {
            float v0 = 0, v1 = 0, v2 = 0, v3 = 0, v4 = 0, v5 = 0;
            for (int w2 = 0; w2 < 4; ++w2) {
                v0 += red[w2 * 6 + 0]; v1 += red[w2 * 6 + 1];
                v2 += red[w2 * 6 + 2]; v3 += red[w2 * 6 + 3];
                v4 += red[w2 * 6 + 4]; v5 += red[w2 * 6 + 5];
            }
            atomicAdd(&simsum[h], v0);      atomicAdd(&simsq[h], v1);
            atomicAdd(&simsum[8 + h], v2);  atomicAdd(&simsq[8 + h], v3);
            atomicAdd(&simsum[16 + h], v4); atomicAdd(&simsq[16 + h], v5);
        }
        return;
    }

    // ---- MODE1 epilogue ----
    if (lane == 0) {
        #pragma unroll
        for (int rr = 0; rr < 8; ++rr) {
            int lrow = wid * 8 + rr;
            ((unsigned short*)&sm[oWr])[lrow * 512 + 0]   = f2bf(e0r[rr]);
            ((unsigned short*)&sm[oWr])[lrow * 512 + 508] = f2bf(e1r[rr]);
        }
    }
    // write retrieved[0] (content), normalized by 1/D
    {
        size_t rb = ((((size_t)0 * 4 + b) * 8 + h) * 1024 + l0) * 128;
        #pragma unroll
        for (int rr = 0; rr < 8; ++rr) {
            int lrow = wid * 8 + rr;
            float inv = 1.f / Drow[rr];
            ret[rb + (size_t)lrow * 128 + lane]      = accc[rr][0] * inv;
            ret[rb + (size_t)lrow * 128 + 64 + lane] = accc[rr][1] * inv;
        }
    }
    // Wr @ emb_v_rpe  (bins 0..508; 509..511 are zero)
    float accr[8][2];
    #pragma unroll
    for (int rr = 0; rr < 8; ++rr) { accr[rr][0] = 0.f; accr[rr][1] = 0.f; }
    for (int rc = 0; rc < 8; ++rc) {
        __syncthreads();
        #pragma unroll
        for (int i = 0; i < 8; ++i) {
            int ff = t + i * 256;
            int r2 = ff >> 5, dv = ff & 31;
            int r = rc * 64 + r2;
            float4 v = (r < 509) ? *(const float4*)(ev + (size_t)r * 128 + dv * 4)
                                 : make_float4(0.f, 0.f, 0.f, 0.f);
            float* dst = &sm[oV + r2 * 129 + dv * 4];
            dst[0] = v.x; dst[1] = v.y; dst[2] = v.z; dst[3] = v.w;
        }
        __syncthreads();
        const unsigned short* wrp = (const unsigned short*)&sm[oWr];
        #pragma unroll 4
        for (int r2 = 0; r2 < 64; ++r2) {
            float v0 = sm[oV + r2 * 129 + lane];
            float v1 = sm[oV + r2 * 129 + 64 + lane];
            int rbin = rc * 64 + r2;
            #pragma unroll
            for (int rr = 0; rr < 8; ++rr) {
                float w = bf2f(wrp[(wid * 8 + rr) * 512 + rbin]);
                accr[rr][0] += w * v0;
                accr[rr][1] += w * v1;
            }
        }
    }
    {
        size_t rb = ((((size_t)1 * 4 + b) * 8 + h) * 1024 + l0) * 128;
        #pragma unroll
        for (int rr = 0; rr < 8; ++rr) {
            int lrow = wid * 8 + rr;
            float inv = 1.f / Drow[rr];
            ret[rb + (size_t)lrow * 128 + lane]      = accr[rr][0] * inv;
            ret[rb + (size_t)lrow * 128 + 64 + lane] = accr[rr][1] * inv;
        }
    }
}

// ---------------------------------------------------------------------------
// K7: per-(s,h,d) sum/sumsq of retrieved over (b,l). grid (8,16)
// ---------------------------------------------------------------------------
__global__ __launch_bounds__(256) void k_outstats(const float* __restrict__ ret,
                                                  float* __restrict__ sum,
                                                  float* __restrict__ sq) {
    const int ch = blockIdx.x * 256 + threadIdx.x;   // s*1024 + h*128 + d
    const int s = ch >> 10, hd = ch & 1023;
    const int h = hd >> 7, d = hd & 127;
    const int row0 = blockIdx.y * 256;
    float sm_ = 0.f, q = 0.f;
    for (int r = 0; r < 256; ++r) {
        int row = row0 + r;
        int b = row >> 10, l = row & 1023;
        float v = ret[((((size_t)s * 4 + b) * 8 + h) * 1024 + l) * 128 + d];
        sm_ += v; q += v * v;
    }
    atomicAdd(&sum[ch], sm_);
    atomicAdd(&sq[ch], q);
}

// ---------------------------------------------------------------------------
// K8: out BN (per (s,h,d) over (b,l)) + sum over s + transpose -> [B,L,DV]
// ---------------------------------------------------------------------------
__global__ __launch_bounds__(256) void k_final(const float* __restrict__ ret,
                                               const float* __restrict__ osum,
                                               const float* __restrict__ osq,
                                               const float* __restrict__ gamma,
                                               const float* __restrict__ beta,
                                               float* __restrict__ out) {
    const int idx = blockIdx.x * 256 + threadIdx.x;  // float4 index
    const int o = idx * 4;
    const int d = o & 127;
    const int h = (o >> 7) & 7;
    const int l = (o >> 10) & 1023;
    const int b = o >> 20;
    const int ch0 = h * 128 + d;            // s=0 channel
    const int ch1 = 1024 + ch0;             // s=1 channel
    float4 r0 = *(const float4*)(ret + ((((size_t)0 * 4 + b) * 8 + h) * 1024 + l) * 128 + d);
    float4 r1 = *(const float4*)(ret + ((((size_t)1 * 4 + b) * 8 + h) * 1024 + l) * 128 + d);
    float4 s0 = *(const float4*)(osum + ch0), q0 = *(const float4*)(osq + ch0);
    float4 s1 = *(const float4*)(osum + ch1), q1 = *(const float4*)(osq + ch1);
    float4 g0 = *(const float4*)(gamma + ch0), b0 = *(const float4*)(beta + ch0);
    float4 g1 = *(const float4*)(gamma + ch1), b1 = *(const float4*)(beta + ch1);
    const float inv = 1.f / 4096.f;
    float4 res;
    {
        float m0 = s0.x*inv, v0 = q0.x*inv - m0*m0, a0 = g0.x*rsqrtf(v0+EPSN);
        float m1 = s1.x*inv, v1 = q1.x*inv - m1*m1, a1 = g1.x*rsqrtf(v1+EPSN);
        res.x = a0*(r0.x-m0)+b0.x + a1*(r1.x-m1)+b1.x;
    }
    {
        float m0 = s0.y*inv, v0 = q0.y*inv - m0*m0, a0 = g0.y*rsqrtf(v0+EPSN);
        float m1 = s1.y*inv, v1 = q1.y*inv - m1*m1, a1 = g1.y*rsqrtf(v1+EPSN);
        res.y = a0*(r0.y-m0)+b0.y + a1*(r1.y-m1)+b1.y;
    }
    {
        float m0 = s0.z*inv, v0 = q0.z*inv - m0*m0, a0 = g0.z*rsqrtf(v0+EPSN);
        float m1 = s1.z*inv, v1 = q1.z*inv - m1*m1, a1 = g1.z*rsqrtf(v1+EPSN);
        res.z = a0*(r0.z-m0)+b0.z + a1*(r1.z-m1)+b1.z;
    }
    {
        float m0 = s0.w*inv, v0 = q0.w*inv - m0*m0, a0 = g0.w*rsqrtf(v0+EPSN);
        float m1 = s1.w*inv, v1 = q1.w*inv - m1*m1, a1 = g1.w*rsqrtf(v1+EPSN);
        res.w = a0*(r0.w-m0)+b0.w + a1*(r1.w-m1)+b1.w;
    }
    *(float4*)(out + o) = res;
}

// ---------------------------------------------------------------------------
extern "C" void kernel_launch(void* const* d_in, const int* in_sizes, int n_in,
                              void* d_out, int out_size, void* d_ws, size_t ws_size,
                              hipStream_t stream) {
    const float* x     = (const float*)d_in[0];
    const float* wqkv  = (const float*)d_in[1];
    const float* g_qkv = (const float*)d_in[2];
    const float* b_qkv = (const float*)d_in[3];
    const float* g_sim = (const float*)d_in[4];
    const float* b_sim = (const float*)d_in[5];
    const float* g_out = (const float*)d_in[6];
    const float* b_out = (const float*)d_in[7];
    const float* eq    = (const float*)d_in[8];
    const float* ek    = (const float*)d_in[9];
    const float* ev    = (const float*)d_in[10];
    float* ws  = (float*)d_ws;
    float* out = (float*)d_out;

    // Defensive: if the workspace is smaller than required, bail out cleanly
    // (diagnosable correctness failure instead of an OOB GPU fault).
    if (ws_size < WS_TOTAL_FLOATS * sizeof(float)) {
        hipMemsetAsync(out, 0, (size_t)out_size * sizeof(float), stream);
        return;
    }

    float* qkv    = ws + WS_QKV;
    float* colsum = ws + WS_COLSUM;
    float* colsq  = ws + WS_COLSQ;
    float* simsum = ws + WS_SIMSUM;
    float* simsq  = ws + WS_SIMSQ;
    float* outsum = ws + WS_OUTSUM;
    float* outsq  = ws + WS_OUTSQ;
    float* qscale = ws + WS_QSCALE;
    float* qshift = ws + WS_QSHIFT;
    float* sim_a  = ws + WS_SIMA;
    float* sim_c  = ws + WS_SIMC;
    float* ret    = ws + WS_RET;

    // opt-in to >64KB dynamic LDS (host-side attribute; safe under capture)
    hipFuncSetAttribute(reinterpret_cast<const void*>(k_attn<0>),
                        hipFuncAttributeMaxDynamicSharedMemorySize, SMEM0_BYTES);
    hipFuncSetAttribute(reinterpret_cast<const void*>(k_attn<1>),
                        hipFuncAttributeMaxDynamicSharedMemorySize, SMEM1_BYTES);

    hipMemsetAsync(ws + WS_STATS, 0, WS_STATS_N * sizeof(float), stream);

    k_gemm_qkv<<<dim3(32, 64), 256, 0, stream>>>(x, wqkv, qkv);
    k_colstats<<<dim3(8, 16), 256, 0, stream>>>(qkv, colsum, colsq);
    k_fold_qkv<<<dim3(8), 256, 0, stream>>>(colsum, colsq, g_qkv, b_qkv, qscale, qshift);
    k_attn<0><<<dim3(1024), 256, SMEM0_BYTES, stream>>>(qkv, qscale, qshift, eq, ek, ev,
                                                        sim_a, sim_c, simsum, simsq, ret);
    k_fold_sim<<<dim3(1), 32, 0, stream>>>(simsum, simsq, g_sim, b_sim, sim_a, sim_c);
    k_attn<1><<<dim3(1024), 256, SMEM1_BYTES, stream>>>(qkv, qscale, qshift, eq, ek, ev,
                                                        sim_a, sim_c, simsum, simsq, ret);
    k_outstats<<<dim3(8, 16), 256, 0, stream>>>(ret, outsum, outsq);
    k_final<<<dim3(4096), 256, 0, stream>>>(ret, outsum, outsq, g_out, b_out, out);
}

// Round 3
// 1386.091 us; speedup vs baseline: 1.5694x; 1.5694x over previous
//
#include <hip/hip_runtime.h>

// ---------------------------------------------------------------------------
// AxialAttention: B=4 L=1024 C=512 DK=512 DV=1024 H=8 DKH=64 DVH=128, R=509
//
// New pipeline (MFMA for sims):
//   K1 gemm_qkv  : qkv = x @ W_qkv (fp32)
//   K2 colstats / K3 fold_qkv
//   G-GEMMs (bf16 MFMA 16x16x32):  S[z,l,m] = Qf@Kf^T per (b,h)
//                                  G1[z*L+l, r] = Qf@eq^T
//                                  G2[z*L+m, r] = Kf@ek^T
//   stats_S / stats_G<1,2> : sim BN stats (clamp multiplicity closed-form)
//   fold_sim
//   k_attn2  : logits from S/G1/G2 tiles -> online softmax -> PV content +
//              Wr-bin rel-PV (LDS 70KB -> 2 blocks/CU, conflict-free reads)
//   outstats / final
// Fallback: if ws_size too small, run the round-2 all-VALU pipeline.
// ---------------------------------------------------------------------------

#define EPSN 1e-5f

// ---- OLD (round-2) workspace layout (float offsets) ----
#define WS_QKV      0ul
#define WS_STATS    8388608ul
#define WS_COLSUM   (WS_STATS)
#define WS_COLSQ    (WS_STATS + 2048)
#define WS_SIMSUM   (WS_STATS + 4096)
#define WS_SIMSQ    (WS_STATS + 4120)
#define WS_OUTSUM   (WS_STATS + 4144)
#define WS_OUTSQ    (WS_STATS + 6192)
#define WS_STATS_N  8240ul
#define WS_FOLD     (WS_STATS + WS_STATS_N)
#define WS_QSCALE   (WS_FOLD)
#define WS_QSHIFT   (WS_FOLD + 2048)
#define WS_SIMA     (WS_FOLD + 4096)
#define WS_SIMC     (WS_FOLD + 4120)
#define WS_RET      (WS_FOLD + 4128)
#define WS_TOTAL_FLOATS (WS_RET + 8388608ul)     // ~67.2 MB

// ---- NEW workspace layout (float offsets) ----
#define NWS_QKV   0ul                   // 8,388,608 f
#define NWS_S     8388608ul             // 33.5M bf16 = 16,777,216 f
#define NWS_G1    25165824ul            // 16.8M bf16 = 8,388,608 f
#define NWS_G2    33554432ul            // 8,388,608 f
#define NWS_RET   41943040ul            // 8,388,608 f (fp32)
#define NWS_STATS 50331648ul
#define NWS_COLSUM (NWS_STATS)
#define NWS_COLSQ  (NWS_STATS + 2048)
#define NWS_SIMSUM (NWS_STATS + 4096)
#define NWS_SIMSQ  (NWS_STATS + 4120)
#define NWS_OUTSUM (NWS_STATS + 4144)
#define NWS_OUTSQ  (NWS_STATS + 6192)
#define NWS_STATS_N 8240ul
#define NWS_FOLD   (NWS_STATS + NWS_STATS_N)
#define NWS_QSCALE (NWS_FOLD)
#define NWS_QSHIFT (NWS_FOLD + 2048)
#define NWS_SIMA   (NWS_FOLD + 4096)
#define NWS_SIMC   (NWS_FOLD + 4120)
#define NWS_TOTAL_FLOATS (NWS_FOLD + 4128ul)     // ~201.4 MB

typedef __attribute__((ext_vector_type(8))) short short8v;
typedef __attribute__((ext_vector_type(4))) float float4v;

__device__ __forceinline__ unsigned short f2bf(float x) {
    union { float f; unsigned int u; } c; c.f = x;
    unsigned int u = c.u + 0x7fffu + ((c.u >> 16) & 1u);   // RNE
    return (unsigned short)(u >> 16);
}
__device__ __forceinline__ float bf2f(unsigned short x) {
    union { unsigned int u; float f; } c; c.u = ((unsigned int)x) << 16;
    return c.f;
}

// ---------------------------------------------------------------------------
// K1: qkv = x[4096,512] @ W[512,2048], fp32 tiled GEMM
// ---------------------------------------------------------------------------
__global__ __launch_bounds__(256) void k_gemm_qkv(const float* __restrict__ x,
                                                  const float* __restrict__ w,
                                                  float* __restrict__ qkv) {
    __shared__ float As[16][68];
    __shared__ float Bs[16][68];
    const int t  = threadIdx.x;
    const int tx = t & 15;
    const int ty = t >> 4;
    const int n0 = blockIdx.x * 64;
    const int r0 = blockIdx.y * 64;
    const int ar = t >> 2, akv = t & 3;
    const int bk = t >> 4, bn = t & 15;
    float acc[4][4];
    #pragma unroll
    for (int i = 0; i < 4; ++i)
        #pragma unroll
        for (int j = 0; j < 4; ++j) acc[i][j] = 0.f;

    for (int k0 = 0; k0 < 512; k0 += 16) {
        __syncthreads();
        float4 av = *(const float4*)(x + (size_t)(r0 + ar) * 512 + k0 + akv * 4);
        As[akv*4+0][ar] = av.x; As[akv*4+1][ar] = av.y;
        As[akv*4+2][ar] = av.z; As[akv*4+3][ar] = av.w;
        float4 bv = *(const float4*)(w + (size_t)(k0 + bk) * 2048 + n0 + bn * 4);
        *(float4*)&Bs[bk][bn*4] = bv;
        __syncthreads();
        #pragma unroll
        for (int kk = 0; kk < 16; ++kk) {
            float4 a = *(const float4*)&As[kk][ty*4];
            float4 b = *(const float4*)&Bs[kk][tx*4];
            acc[0][0] += a.x*b.x; acc[0][1] += a.x*b.y; acc[0][2] += a.x*b.z; acc[0][3] += a.x*b.w;
            acc[1][0] += a.y*b.x; acc[1][1] += a.y*b.y; acc[1][2] += a.y*b.z; acc[1][3] += a.y*b.w;
            acc[2][0] += a.z*b.x; acc[2][1] += a.z*b.y; acc[2][2] += a.z*b.z; acc[2][3] += a.z*b.w;
            acc[3][0] += a.w*b.x; acc[3][1] += a.w*b.y; acc[3][2] += a.w*b.z; acc[3][3] += a.w*b.w;
        }
    }
    #pragma unroll
    for (int i = 0; i < 4; ++i) {
        float4 o = make_float4(acc[i][0], acc[i][1], acc[i][2], acc[i][3]);
        *(float4*)(qkv + (size_t)(r0 + ty*4 + i) * 2048 + n0 + tx*4) = o;
    }
}

// ---------------------------------------------------------------------------
// K2/K3: qkv BN stats + fold
// ---------------------------------------------------------------------------
__global__ __launch_bounds__(256) void k_colstats(const float* __restrict__ src,
                                                  float* __restrict__ sum,
                                                  float* __restrict__ sq) {
    const int ch = blockIdx.x * 256 + threadIdx.x;
    const int r0 = blockIdx.y * 256;
    float s = 0.f, q = 0.f;
    for (int r = 0; r < 256; ++r) {
        float v = src[(size_t)(r0 + r) * 2048 + ch];
        s += v; q += v * v;
    }
    atomicAdd(&sum[ch], s);
    atomicAdd(&sq[ch], q);
}

__global__ __launch_bounds__(256) void k_fold_qkv(const float* __restrict__ sum,
                                                  const float* __restrict__ sq,
                                                  const float* __restrict__ gamma,
                                                  const float* __restrict__ beta,
                                                  float* __restrict__ scale,
                                                  float* __restrict__ shift) {
    const int ch = blockIdx.x * 256 + threadIdx.x;
    float m = sum[ch] * (1.f / 4096.f);
    float v = sq[ch] * (1.f / 4096.f) - m * m;
    float sc = gamma[ch] * rsqrtf(v + EPSN);
    scale[ch] = sc;
    shift[ch] = beta[ch] - sc * m;
}

__global__ void k_fold_sim(const float* __restrict__ simsum,
                           const float* __restrict__ simsq,
                           const float* __restrict__ gamma,
                           const float* __restrict__ beta,
                           float* __restrict__ a_out,
                           float* __restrict__ c_out) {
    __shared__ float part[24];
    const int t = threadIdx.x;
    const float inv = 1.f / (4.f * 1024.f * 1024.f);
    if (t < 24) {
        float m = simsum[t] * inv;
        float v = simsq[t] * inv - m * m;
        float a = gamma[t] * rsqrtf(v + EPSN);
        a_out[t] = a;
        part[t] = beta[t] - a * m;
    }
    __syncthreads();
    if (t < 8) c_out[t] = part[t] + part[8 + t] + part[16 + t];
}

// ---------------------------------------------------------------------------
// NEW: bf16 MFMA GEMM  C = fold(A) @ fold(B)^T  (K=64), C written bf16.
// GM=0: S per (b,h) [1024x1024]; GM=1: G1 [32768x512]; GM=2: G2 [32768x512]
// LDS tiles 64x64 bf16, XOR-swizzled (byte ^= (row&7)<<4 on 16B slots).
// ---------------------------------------------------------------------------
template<int GM>
__global__ __launch_bounds__(256) void k_gemm_bt(
        const float* __restrict__ qkv,
        const float* __restrict__ qscale, const float* __restrict__ qshift,
        const float* __restrict__ emb,
        unsigned short* __restrict__ outp) {
    __shared__ unsigned short Ab[64 * 64];
    __shared__ unsigned short Bb[64 * 64];
    const int t = threadIdx.x;
    const int lane = t & 63, w = t >> 6;
    const int n0 = blockIdx.x * 64;
    const int m0 = blockIdx.y * 64;
    const int z  = blockIdx.z;
    const int sr = t >> 2, sc = (t & 3) * 16;

    // ---- stage A (always from qkv, folded) ----
    {
        int grow = m0 + sr;
        const float* src; int ch;
        if (GM == 0) {
            int b = z >> 3, h = z & 7;
            ch = h * 64 + sc;
            src = qkv + ((size_t)(b * 1024 + grow)) * 2048 + ch;
        } else {
            int zz = grow >> 10, l = grow & 1023;
            int b = zz >> 3, h = zz & 7;
            ch = (GM == 2 ? 512 : 0) + h * 64 + sc;
            src = qkv + ((size_t)(b * 1024 + l)) * 2048 + ch;
        }
        unsigned short tmp[16];
        #pragma unroll
        for (int i = 0; i < 4; ++i) {
            float4 v  = *(const float4*)(src + i * 4);
            float4 s4 = *(const float4*)(qscale + ch + i * 4);
            float4 h4 = *(const float4*)(qshift + ch + i * 4);
            tmp[i*4+0] = f2bf(v.x*s4.x+h4.x); tmp[i*4+1] = f2bf(v.y*s4.y+h4.y);
            tmp[i*4+2] = f2bf(v.z*s4.z+h4.z); tmp[i*4+3] = f2bf(v.w*s4.w+h4.w);
        }
        int x0 = (sc * 2) ^ ((sr & 7) << 4);
        int x1 = ((sc * 2) + 16) ^ ((sr & 7) << 4);
        *(uint4*)((char*)Ab + sr * 128 + x0) = *(uint4*)&tmp[0];
        *(uint4*)((char*)Ab + sr * 128 + x1) = *(uint4*)&tmp[8];
    }
    // ---- stage B ----
    {
        unsigned short tmp[16];
        if (GM == 0) {
            int b = z >> 3, h = z & 7;
            int ch = 512 + h * 64 + sc;
            const float* src = qkv + ((size_t)(b * 1024 + n0 + sr)) * 2048 + ch;
            #pragma unroll
            for (int i = 0; i < 4; ++i) {
                float4 v  = *(const float4*)(src + i * 4);
                float4 s4 = *(const float4*)(qscale + ch + i * 4);
                float4 h4 = *(const float4*)(qshift + ch + i * 4);
                tmp[i*4+0] = f2bf(v.x*s4.x+h4.x); tmp[i*4+1] = f2bf(v.y*s4.y+h4.y);
                tmp[i*4+2] = f2bf(v.z*s4.z+h4.z); tmp[i*4+3] = f2bf(v.w*s4.w+h4.w);
            }
        } else {
            int r = n0 + sr;
            if (r < 509) {
                const float* src = emb + (size_t)r * 64 + sc;
                #pragma unroll
                for (int i = 0; i < 4; ++i) {
                    float4 v = *(const float4*)(src + i * 4);
                    tmp[i*4+0] = f2bf(v.x); tmp[i*4+1] = f2bf(v.y);
                    tmp[i*4+2] = f2bf(v.z); tmp[i*4+3] = f2bf(v.w);
                }
            } else {
                #pragma unroll
                for (int i = 0; i < 16; ++i) tmp[i] = 0;
            }
        }
        int x0 = (sc * 2) ^ ((sr & 7) << 4);
        int x1 = ((sc * 2) + 16) ^ ((sr & 7) << 4);
        *(uint4*)((char*)Bb + sr * 128 + x0) = *(uint4*)&tmp[0];
        *(uint4*)((char*)Bb + sr * 128 + x1) = *(uint4*)&tmp[8];
    }
    __syncthreads();

    // ---- MFMA: wave w -> rows w*16..w*16+15, all 64 cols ----
    const int fr = lane & 15, kg = lane >> 4;
    float4v acc[4];
    #pragma unroll
    for (int nt = 0; nt < 4; ++nt) { acc[nt][0]=0.f; acc[nt][1]=0.f; acc[nt][2]=0.f; acc[nt][3]=0.f; }
    #pragma unroll
    for (int ks = 0; ks < 2; ++ks) {
        int arow = w * 16 + fr;
        short8v a = *(short8v*)((char*)Ab + arow * 128 +
                                ((kg * 16 + ks * 64) ^ ((arow & 7) << 4)));
        #pragma unroll
        for (int nt = 0; nt < 4; ++nt) {
            int brow = nt * 16 + fr;
            short8v bf = *(short8v*)((char*)Bb + brow * 128 +
                                     ((kg * 16 + ks * 64) ^ ((brow & 7) << 4)));
            acc[nt] = __builtin_amdgcn_mfma_f32_16x16x32_bf16(a, bf, acc[nt], 0, 0, 0);
        }
    }

    // ---- C write (bf16): row=(lane>>4)*4+j, col=lane&15 ----
    const int crow = (lane >> 4) * 4;
    const int ccol = lane & 15;
    size_t base; int ldc;
    if (GM == 0) { base = (((size_t)z * 1024) + m0 + w * 16) * 1024 + n0; ldc = 1024; }
    else         { base = ((size_t)(m0 + w * 16)) * 512 + n0;             ldc = 512;  }
    #pragma unroll
    for (int nt = 0; nt < 4; ++nt)
        #pragma unroll
        for (int j = 0; j < 4; ++j)
            outp[base + (size_t)(crow + j) * ldc + nt * 16 + ccol] = f2bf(acc[nt][j]);
}

// ---------------------------------------------------------------------------
// NEW: sim BN stats.
// ---------------------------------------------------------------------------
__global__ __launch_bounds__(256) void k_stats_S(const unsigned short* __restrict__ S,
                                                 float* __restrict__ simsum,
                                                 float* __restrict__ simsq) {
    const int z = blockIdx.x, chunk = blockIdx.y;
    const int h = z & 7;
    const int lane = threadIdx.x & 63;
    size_t base = (size_t)z * 1048576 + (size_t)chunk * 65536;
    float s = 0.f, q = 0.f;
    for (int i = 0; i < 32; ++i) {
        uint4 v = *(const uint4*)(S + base + (size_t)(i * 256 + threadIdx.x) * 8);
        const unsigned short* p = (const unsigned short*)&v;
        #pragma unroll
        for (int j = 0; j < 8; ++j) { float x = bf2f(p[j]); s += x; q += x * x; }
    }
    #pragma unroll
    for (int off = 32; off; off >>= 1) { s += __shfl_xor(s, off); q += __shfl_xor(q, off); }
    if (lane == 0) { atomicAdd(&simsum[h], s); atomicAdd(&simsq[h], q); }
}

// Weighted stats over G (clamp multiplicities). WHICH=1: rows are l (q-rpe);
// WHICH=2: rows are m (k-rpe). Atomic to simsum[8*WHICH+h].
template<int WHICH>
__global__ __launch_bounds__(256) void k_stats_G(const unsigned short* __restrict__ G,
                                                 float* __restrict__ simsum,
                                                 float* __restrict__ simsq) {
    const int z = blockIdx.x, lg = blockIdx.y;
    const int h = z & 7;
    const int lane = threadIdx.x & 63, wid = threadIdx.x >> 6;
    float s = 0.f, q = 0.f;
    for (int rr = 0; rr < 16; ++rr) {
        int row = lg * 64 + wid * 16 + rr;
        const unsigned short* g = G + ((size_t)z * 1024 + row) * 512;
        int c0, c508, rlo, rhi;
        if (WHICH == 1) {
            c0 = row - 253 > 0 ? row - 253 : 0;
            c508 = 770 - row > 0 ? 770 - row : 0;
            rlo = 254 - row > 1 ? 254 - row : 1;
            rhi = 1277 - row < 507 ? 1277 - row : 507;
        } else {
            c0 = 770 - row > 0 ? 770 - row : 0;
            c508 = row - 253 > 0 ? row - 253 : 0;
            rlo = row - 769 > 1 ? row - 769 : 1;
            rhi = row + 254 < 507 ? row + 254 : 507;
        }
        #pragma unroll
        for (int i = 0; i < 8; ++i) {
            int r = lane + i * 64;
            float mult = (r == 0) ? (float)c0
                       : (r == 508) ? (float)c508
                       : (r >= rlo && r <= rhi) ? 1.f : 0.f;
            float v = bf2f(g[r]);
            s += mult * v; q += mult * v * v;
        }
    }
    #pragma unroll
    for (int off = 32; off; off >>= 1) { s += __shfl_xor(s, off); q += __shfl_xor(q, off); }
    if (lane == 0) { atomicAdd(&simsum[8 * WHICH + h], s); atomicAdd(&simsq[8 * WHICH + h], q); }
}

// ---------------------------------------------------------------------------
// NEW Pass B: logits from S/G1/G2 -> online softmax -> PV + Wr rel-PV.
// Block = (b,h,32-row l-tile), 256 thr. LDS ~69.8KB -> 2 blocks/CU.
// LDS (ushort offsets): S[32][72]@0, G1[32][72]@2304, G2[64][34]@4608,
//                       V bf16[64][128]@6784, Ws f32[32][68]@f7488, Wr@s19328
// ---------------------------------------------------------------------------
#define sS2  0
#define sG1w 2304
#define sG2w 4608
#define sV2  6784
#define fWs2 7488
#define sWr2 19328
#define SMEMB_BYTES 71424

__global__ __launch_bounds__(256) void k_attn2(
        const float* __restrict__ qkv,
        const float* __restrict__ qscale, const float* __restrict__ qshift,
        const unsigned short* __restrict__ Sg,
        const unsigned short* __restrict__ G1g,
        const unsigned short* __restrict__ G2g,
        const float* __restrict__ ev,
        const float* __restrict__ sim_a, const float* __restrict__ sim_c,
        float* __restrict__ ret) {
    extern __shared__ float sm[];
    unsigned short* su = (unsigned short*)sm;
    const int t = threadIdx.x;
    const int lane = t & 63, wid = t >> 6;
    const int blk = blockIdx.x;
    const int lt = blk & 31;
    const int h  = (blk >> 5) & 7;
    const int b  = blk >> 8;
    const int l0 = lt * 32;
    const int z  = b * 8 + h;
    const size_t bbase = (size_t)b * 1024 * 2048;
    const size_t zS = (size_t)z * 1048576;
    const size_t zG = (size_t)z * 1024 * 512;

    float Mrow[8], Drow[8], e0r[8], e1r[8], accc[8][2];
    #pragma unroll
    for (int r = 0; r < 8; ++r) {
        Mrow[r] = -1e30f; Drow[r] = 0.f; e0r[r] = 0.f; e1r[r] = 0.f;
        accc[r][0] = 0.f; accc[r][1] = 0.f;
    }
    {   // zero Wr
        unsigned int* wz = (unsigned int*)(su + sWr2);
        for (int i = t; i < 8192; i += 256) wz[i] = 0u;
    }
    const float a0c = sim_a[h], a1c = sim_a[8 + h], a2c = sim_a[16 + h], cc = sim_c[h];

    for (int mt = 0; mt < 16; ++mt) {
        const int m0 = mt * 64;
        __syncthreads();
        // ---- stage S tile [32][64] ----
        {
            int row = t >> 3, j0 = (t & 7) * 8;
            *(uint4*)(su + sS2 + row * 72 + j0) =
                *(const uint4*)(Sg + zS + (size_t)(l0 + row) * 1024 + m0 + j0);
        }
        // ---- stage G1 window [32][64] (clamped contiguous) ----
        {
            int row = t >> 3, j0 = (t & 7) * 8;
            const unsigned short* gr = G1g + zG + (size_t)(l0 + row) * 512;
            int rbase = m0 + j0 - (l0 + row) + 254;
            #pragma unroll
            for (int j = 0; j < 8; ++j) {
                int r = rbase + j; r = r < 0 ? 0 : (r > 508 ? 508 : r);
                su[sG1w + row * 72 + j0 + j] = gr[r];
            }
        }
        // ---- stage G2 window [64][32] (clamped, reversed-contiguous) ----
        {
            int i = t >> 2, lr0 = (t & 3) * 8;
            const unsigned short* gr = G2g + zG + (size_t)(m0 + i) * 512;
            int rbase = m0 + i - l0 + 254;
            #pragma unroll
            for (int j = 0; j < 8; ++j) {
                int r = rbase - (lr0 + j); r = r < 0 ? 0 : (r > 508 ? 508 : r);
                su[sG2w + i * 34 + lr0 + j] = gr[r];
            }
        }
        // ---- stage V bf16 [64][128], folded ----
        {
            int m = t >> 2, cg = (t & 3) * 32;
            int ch = 1024 + h * 128 + cg;
            const float* src = qkv + bbase + (size_t)(m0 + m) * 2048 + ch;
            unsigned short tmp[32];
            #pragma unroll
            for (int i = 0; i < 8; ++i) {
                float4 v  = *(const float4*)(src + i * 4);
                float4 s4 = *(const float4*)(qscale + ch + i * 4);
                float4 h4 = *(const float4*)(qshift + ch + i * 4);
                tmp[i*4+0] = f2bf(v.x*s4.x+h4.x); tmp[i*4+1] = f2bf(v.y*s4.y+h4.y);
                tmp[i*4+2] = f2bf(v.z*s4.z+h4.z); tmp[i*4+3] = f2bf(v.w*s4.w+h4.w);
            }
            #pragma unroll
            for (int i = 0; i < 4; ++i)
                *(uint4*)(su + sV2 + m * 128 + cg + i * 8) = *(uint4*)&tmp[i * 8];
        }
        __syncthreads();

        // ---- logits + online softmax (lanes over m) ----
        #pragma unroll
        for (int rr = 0; rr < 8; ++rr) {
            const int lrow = wid * 8 + rr;
            float sval = bf2f(su[sS2  + lrow * 72 + lane]);
            float g1   = bf2f(su[sG1w + lrow * 72 + lane]);
            float g2   = bf2f(su[sG2w + lane * 34 + lrow]);
            float logit = cc + a0c * sval + a1c * g1 + a2c * g2;
            float tm = logit;
            #pragma unroll
            for (int off = 32; off; off >>= 1) tm = fmaxf(tm, __shfl_xor(tm, off));
            float M = Mrow[rr];
            if (tm > M + 8.f) {               // defer-max
                float scl = __expf(M - tm);
                Drow[rr] *= scl; accc[rr][0] *= scl; accc[rr][1] *= scl;
                e0r[rr] *= scl; e1r[rr] *= scl;
                unsigned short* wrp = su + sWr2 + lrow * 512;
                #pragma unroll
                for (int ii = 0; ii < 8; ++ii) {
                    int idx = lane + ii * 64;
                    wrp[idx] = f2bf(bf2f(wrp[idx]) * scl);
                }
                M = tm; Mrow[rr] = tm;
            }
            float wv = __expf(logit - M);
            float ts = wv;
            #pragma unroll
            for (int off = 32; off; off >>= 1) ts += __shfl_xor(ts, off);
            Drow[rr] += ts;
            const int l_g = l0 + lrow;
            const int r_raw = m0 + lane - l_g + 254;
            const bool lo = r_raw <= 0, hi = r_raw >= 508;
            if (m0 - l_g + 254 <= 0) {
                float ew = lo ? wv : 0.f;
                #pragma unroll
                for (int off = 32; off; off >>= 1) ew += __shfl_xor(ew, off);
                e0r[rr] += ew;
            }
            if (m0 + 63 - l_g + 254 >= 508) {
                float ew = hi ? wv : 0.f;
                #pragma unroll
                for (int off = 32; off; off >>= 1) ew += __shfl_xor(ew, off);
                e1r[rr] += ew;
            }
            if (!lo && !hi)
                su[sWr2 + lrow * 512 + r_raw] = f2bf(wv);
            sm[fWs2 + lrow * 68 + lane] = wv;
        }

        // ---- PV content (lanes over d) ----
        #pragma unroll 2
        for (int m4 = 0; m4 < 16; ++m4) {
            float4 wv4[8];
            #pragma unroll
            for (int rr = 0; rr < 8; ++rr)
                wv4[rr] = *(const float4*)&sm[fWs2 + (wid * 8 + rr) * 68 + m4 * 4];
            #pragma unroll
            for (int mm = 0; mm < 4; ++mm) {
                int m = m4 * 4 + mm;
                float v0 = bf2f(su[sV2 + m * 128 + lane]);
                float v1 = bf2f(su[sV2 + m * 128 + 64 + lane]);
                #pragma unroll
                for (int rr = 0; rr < 8; ++rr) {
                    float w = mm == 0 ? wv4[rr].x : mm == 1 ? wv4[rr].y
                            : mm == 2 ? wv4[rr].z : wv4[rr].w;
                    accc[rr][0] += w * v0;
                    accc[rr][1] += w * v1;
                }
            }
        }
    }

    // ---- epilogue ----
    if (lane == 0) {
        #pragma unroll
        for (int rr = 0; rr < 8; ++rr) {
            int lrow = wid * 8 + rr;
            su[sWr2 + lrow * 512 + 0]   = f2bf(e0r[rr]);
            su[sWr2 + lrow * 512 + 508] = f2bf(e1r[rr]);
        }
    }
    {
        size_t rb = ((((size_t)0 * 4 + b) * 8 + h) * 1024 + l0) * 128;
        #pragma unroll
        for (int rr = 0; rr < 8; ++rr) {
            int lrow = wid * 8 + rr;
            float inv = 1.f / Drow[rr];
            ret[rb + (size_t)lrow * 128 + lane]      = accc[rr][0] * inv;
            ret[rb + (size_t)lrow * 128 + 64 + lane] = accc[rr][1] * inv;
        }
    }
    // Wr @ emb_v_rpe
    float accr[8][2];
    #pragma unroll
    for (int rr = 0; rr < 8; ++rr) { accr[rr][0] = 0.f; accr[rr][1] = 0.f; }
    for (int rc = 0; rc < 8; ++rc) {
        __syncthreads();
        {
            int r2 = t >> 2, cg = (t & 3) * 32;
            int r = rc * 64 + r2;
            unsigned short tmp[32];
            if (r < 509) {
                const float* src = ev + (size_t)r * 128 + cg;
                #pragma unroll
                for (int i = 0; i < 8; ++i) {
                    float4 v = *(const float4*)(src + i * 4);
                    tmp[i*4+0] = f2bf(v.x); tmp[i*4+1] = f2bf(v.y);
                    tmp[i*4+2] = f2bf(v.z); tmp[i*4+3] = f2bf(v.w);
                }
            } else {
                #pragma unroll
                for (int i = 0; i < 32; ++i) tmp[i] = 0;
            }
            #pragma unroll
            for (int i = 0; i < 4; ++i)
                *(uint4*)(su + sV2 + r2 * 128 + cg + i * 8) = *(uint4*)&tmp[i * 8];
        }
        __syncthreads();
        #pragma unroll 4
        for (int r2 = 0; r2 < 64; ++r2) {
            float v0 = bf2f(su[sV2 + r2 * 128 + lane]);
            float v1 = bf2f(su[sV2 + r2 * 128 + 64 + lane]);
            int rbin = rc * 64 + r2;
            #pragma unroll
            for (int rr = 0; rr < 8; ++rr) {
                float w = bf2f(su[sWr2 + (wid * 8 + rr) * 512 + rbin]);
                accr[rr][0] += w * v0;
                accr[rr][1] += w * v1;
            }
        }
    }
    {
        size_t rb = ((((size_t)1 * 4 + b) * 8 + h) * 1024 + l0) * 128;
        #pragma unroll
        for (int rr = 0; rr < 8; ++rr) {
            int lrow = wid * 8 + rr;
            float inv = 1.f / Drow[rr];
            ret[rb + (size_t)lrow * 128 + lane]      = accr[rr][0] * inv;
            ret[rb + (size_t)lrow * 128 + 64 + lane] = accr[rr][1] * inv;
        }
    }
}

// ---------------------------------------------------------------------------
// OLD round-2 attention kernel (fallback path only)
// ---------------------------------------------------------------------------
#define oQ  0
#define oK  2176
#define oQR 6528
#define oKR 12988
#define oV  19448
#define oWs 27704
#define oWr 29880
#define SMEM0_BYTES ((19448 + 32) * 4)
#define SMEM1_BYTES ((29880 + 8192) * 4)

template <int MODE>
__global__ __launch_bounds__(256) void k_attn(
        const float* __restrict__ qkv,
        const float* __restrict__ qscale, const float* __restrict__ qshift,
        const float* __restrict__ eq, const float* __restrict__ ek,
        const float* __restrict__ ev,
        const float* __restrict__ sim_a, const float* __restrict__ sim_c,
        float* __restrict__ simsum, float* __restrict__ simsq,
        float* __restrict__ ret) {
    extern __shared__ float sm[];
    const int t = threadIdx.x;
    const int lane = t & 63, wid = t >> 6;
    const int blk = blockIdx.x;
    const int lt = blk & 31;
    const int h  = (blk >> 5) & 7;
    const int b  = blk >> 8;
    const int l0 = lt * 32;
    const size_t bbase = (size_t)b * 1024 * 2048;

    #pragma unroll
    for (int i = 0; i < 2; ++i) {
        int ff = t + i * 256;
        int row = ff >> 4, dv = ff & 15;
        int ch = h * 64 + dv * 4;
        float4 v   = *(const float4*)(qkv + bbase + (size_t)(l0 + row) * 2048 + ch);
        float4 sc4 = *(const float4*)(qscale + ch);
        float4 sh4 = *(const float4*)(qshift + ch);
        float* dst = &sm[oQ + row * 68 + dv * 4];
        dst[0] = v.x * sc4.x + sh4.x; dst[1] = v.y * sc4.y + sh4.y;
        dst[2] = v.z * sc4.z + sh4.z; dst[3] = v.w * sc4.w + sh4.w;
    }

    float Mrow[8], Drow[8], e0r[8], e1r[8], accc[8][2];
    if (MODE) {
        #pragma unroll
        for (int r = 0; r < 8; ++r) {
            Mrow[r] = -1e30f; Drow[r] = 0.f; e0r[r] = 0.f; e1r[r] = 0.f;
            accc[r][0] = 0.f; accc[r][1] = 0.f;
        }
        unsigned int* wz = (unsigned int*)&sm[oWr];
        for (int i = t; i < 8192; i += 256) wz[i] = 0u;
    }
    float s0 = 0, q0 = 0, s1 = 0, q1 = 0, s2 = 0, q2 = 0;
    float a0c = 0, a1c = 0, a2c = 0, cc = 0;
    if (MODE) {
        a0c = sim_a[h]; a1c = sim_a[8 + h]; a2c = sim_a[16 + h]; cc = sim_c[h];
    }

    for (int mt = 0; mt < 16; ++mt) {
        const int m0 = mt * 64;
        __syncthreads();
        #pragma unroll
        for (int i = 0; i < 4; ++i) {
            int ff = t + i * 256;
            int m = ff >> 4, dv = ff & 15;
            int ch = 512 + h * 64 + dv * 4;
            float4 v   = *(const float4*)(qkv + bbase + (size_t)(m0 + m) * 2048 + ch);
            float4 sc4 = *(const float4*)(qscale + ch);
            float4 sh4 = *(const float4*)(qshift + ch);
            float* dst = &sm[oK + m * 68 + dv * 4];
            dst[0] = v.x * sc4.x + sh4.x; dst[1] = v.y * sc4.y + sh4.y;
            dst[2] = v.z * sc4.z + sh4.z; dst[3] = v.w * sc4.w + sh4.w;
        }
        {
            const int rmin = m0 - l0 + 223;
            for (int ff = t; ff < 1520; ff += 256) {
                int j = ff >> 4, dv = ff & 15;
                int r = rmin + j; r = r < 0 ? 0 : (r > 508 ? 508 : r);
                float4 v1 = *(const float4*)(eq + (size_t)r * 64 + dv * 4);
                float* d1 = &sm[oQR + j * 68 + dv * 4];
                d1[0] = v1.x; d1[1] = v1.y; d1[2] = v1.z; d1[3] = v1.w;
                float4 v2 = *(const float4*)(ek + (size_t)r * 64 + dv * 4);
                float* d2 = &sm[oKR + j * 68 + dv * 4];
                d2[0] = v2.x; d2[1] = v2.y; d2[2] = v2.z; d2[3] = v2.w;
            }
        }
        if (MODE) {
            #pragma unroll
            for (int i = 0; i < 8; ++i) {
                int ff = t + i * 256;
                int m = ff >> 5, dv = ff & 31;
                int ch = 1024 + h * 128 + dv * 4;
                float4 v   = *(const float4*)(qkv + bbase + (size_t)(m0 + m) * 2048 + ch);
                float4 sc4 = *(const float4*)(qscale + ch);
                float4 sh4 = *(const float4*)(qshift + ch);
                float* dst = &sm[oV + m * 129 + dv * 4];
                dst[0] = v.x * sc4.x + sh4.x; dst[1] = v.y * sc4.y + sh4.y;
                dst[2] = v.z * sc4.z + sh4.z; dst[3] = v.w * sc4.w + sh4.w;
            }
        }
        __syncthreads();

        #pragma unroll
        for (int rr = 0; rr < 8; ++rr) {
            const int lrow = wid * 8 + rr;
            const int jj = lane - lrow + 31;
            const float* qp  = &sm[oQ  + lrow * 68];
            const float* kp  = &sm[oK  + lane * 68];
            const float* qrp = &sm[oQR + jj * 68];
            const float* krp = &sm[oKR + jj * 68];
            float A0 = 0.f, A1 = 0.f, A2 = 0.f;
            #pragma unroll 4
            for (int d4 = 0; d4 < 16; ++d4) {
                float4 q  = *(const float4*)(qp  + d4 * 4);
                float4 k  = *(const float4*)(kp  + d4 * 4);
                float4 qr = *(const float4*)(qrp + d4 * 4);
                float4 kr = *(const float4*)(krp + d4 * 4);
                A0 += q.x*k.x  + q.y*k.y  + q.z*k.z  + q.w*k.w;
                A1 += q.x*qr.x + q.y*qr.y + q.z*qr.z + q.w*qr.w;
                A2 += k.x*kr.x + k.y*kr.y + k.z*kr.z + k.w*kr.w;
            }
            if (MODE == 0) {
                s0 += A0; q0 += A0 * A0;
                s1 += A1; q1 += A1 * A1;
                s2 += A2; q2 += A2 * A2;
            } else {
                float logit = cc + a0c * A0 + a1c * A1 + a2c * A2;
                float tm = logit;
                #pragma unroll
                for (int off = 32; off; off >>= 1) tm = fmaxf(tm, __shfl_xor(tm, off));
                float M = Mrow[rr];
                if (tm > M + 8.f) {
                    float scl = __expf(M - tm);
                    Drow[rr] *= scl; accc[rr][0] *= scl; accc[rr][1] *= scl;
                    e0r[rr] *= scl; e1r[rr] *= scl;
                    unsigned short* wrp = (unsigned short*)&sm[oWr] + lrow * 512;
                    #pragma unroll
                    for (int ii = 0; ii < 8; ++ii) {
                        int idx = lane + ii * 64;
                        wrp[idx] = f2bf(bf2f(wrp[idx]) * scl);
                    }
                    M = tm; Mrow[rr] = tm;
                }
                float wv = __expf(logit - M);
                float ts = wv;
                #pragma unroll
                for (int off = 32; off; off >>= 1) ts += __shfl_xor(ts, off);
                Drow[rr] += ts;
                const int l_g = l0 + lrow;
                const int r_raw = m0 + lane - l_g + 254;
                const bool lo = r_raw <= 0, hi = r_raw >= 508;
                if (m0 - l_g + 254 <= 0) {
                    float ew = lo ? wv : 0.f;
                    #pragma unroll
                    for (int off = 32; off; off >>= 1) ew += __shfl_xor(ew, off);
                    e0r[rr] += ew;
                }
                if (m0 + 63 - l_g + 254 >= 508) {
                    float ew = hi ? wv : 0.f;
                    #pragma unroll
                    for (int off = 32; off; off >>= 1) ew += __shfl_xor(ew, off);
                    e1r[rr] += ew;
                }
                if (!lo && !hi)
                    ((unsigned short*)&sm[oWr])[lrow * 512 + r_raw] = f2bf(wv);
                sm[oWs + lrow * 68 + lane] = wv;
            }
        }

        if (MODE) {
            #pragma unroll 2
            for (int m4 = 0; m4 < 16; ++m4) {
                float4 wv4[8];
                #pragma unroll
                for (int rr = 0; rr < 8; ++rr)
                    wv4[rr] = *(const float4*)&sm[oWs + (wid * 8 + rr) * 68 + m4 * 4];
                #pragma unroll
                for (int mm = 0; mm < 4; ++mm) {
                    int m = m4 * 4 + mm;
                    float v0 = sm[oV + m * 129 + lane];
                    float v1 = sm[oV + m * 129 + 64 + lane];
                    #pragma unroll
                    for (int rr = 0; rr < 8; ++rr) {
                        float w = mm == 0 ? wv4[rr].x : mm == 1 ? wv4[rr].y
                                : mm == 2 ? wv4[rr].z : wv4[rr].w;
                        accc[rr][0] += w * v0;
                        accc[rr][1] += w * v1;
                    }
                }
            }
        }
    }

    if (MODE == 0) {
        #pragma unroll
        for (int off = 32; off; off >>= 1) {
            s0 += __shfl_xor(s0, off); q0 += __shfl_xor(q0, off);
            s1 += __shfl_xor(s1, off); q1 += __shfl_xor(q1, off);
            s2 += __shfl_xor(s2, off); q2 += __shfl_xor(q2, off);
        }
        __syncthreads();
        float* red = &sm[oV];
        if (lane == 0) {
            red[wid * 6 + 0] = s0; red[wid * 6 + 1] = q0;
            red[wid * 6 + 2] = s1; red[wid * 6 + 3] = q1;
            red[wid * 6 + 4] = s2; red[wid * 6 + 5] = q2;
        }
        __syncthreads();
        if (t == 0) {
            float v0 = 0, v1 = 0, v2 = 0, v3 = 0, v4 = 0, v5 = 0;
            for (int w2 = 0; w2 < 4; ++w2) {
                v0 += red[w2 * 6 + 0]; v1 += red[w2 * 6 + 1];
                v2 += red[w2 * 6 + 2]; v3 += red[w2 * 6 + 3];
                v4 += red[w2 * 6 + 4]; v5 += red[w2 * 6 + 5];
            }
            atomicAdd(&simsum[h], v0);      atomicAdd(&simsq[h], v1);
            atomicAdd(&simsum[8 + h], v2);  atomicAdd(&simsq[8 + h], v3);
            atomicAdd(&simsum[16 + h], v4); atomicAdd(&simsq[16 + h], v5);
        }
        return;
    }

    if (lane == 0) {
        #pragma unroll
        for (int rr = 0; rr < 8; ++rr) {
            int lrow = wid * 8 + rr;
            ((unsigned short*)&sm[oWr])[lrow * 512 + 0]   = f2bf(e0r[rr]);
            ((unsigned short*)&sm[oWr])[lrow * 512 + 508] = f2bf(e1r[rr]);
        }
    }
    {
        size_t rb = ((((size_t)0 * 4 + b) * 8 + h) * 1024 + l0) * 128;
        #pragma unroll
        for (int rr = 0; rr < 8; ++rr) {
            int lrow = wid * 8 + rr;
            float inv = 1.f / Drow[rr];
            ret[rb + (size_t)lrow * 128 + lane]      = accc[rr][0] * inv;
            ret[rb + (size_t)lrow * 128 + 64 + lane] = accc[rr][1] * inv;
        }
    }
    float accr[8][2];
    #pragma unroll
    for (int rr = 0; rr < 8; ++rr) { accr[rr][0] = 0.f; accr[rr][1] = 0.f; }
    for (int rc = 0; rc < 8; ++rc) {
        __syncthreads();
        #pragma unroll
        for (int i = 0; i < 8; ++i) {
            int ff = t + i * 256;
            int r2 = ff >> 5, dv = ff & 31;
            int r = rc * 64 + r2;
            float4 v = (r < 509) ? *(const float4*)(ev + (size_t)r * 128 + dv * 4)
                                 : make_float4(0.f, 0.f, 0.f, 0.f);
            float* dst = &sm[oV + r2 * 129 + dv * 4];
            dst[0] = v.x; dst[1] = v.y; dst[2] = v.z; dst[3] = v.w;
        }
        __syncthreads();
        const unsigned short* wrp = (const unsigned short*)&sm[oWr];
        #pragma unroll 4
        for (int r2 = 0; r2 < 64; ++r2) {
            float v0 = sm[oV + r2 * 129 + lane];
            float v1 = sm[oV + r2 * 129 + 64 + lane];
            int rbin = rc * 64 + r2;
            #pragma unroll
            for (int rr = 0; rr < 8; ++rr) {
                float w = bf2f(wrp[(wid * 8 + rr) * 512 + rbin]);
                accr[rr][0] += w * v0;
                accr[rr][1] += w * v1;
            }
        }
    }
    {
        size_t rb = ((((size_t)1 * 4 + b) * 8 + h) * 1024 + l0) * 128;
        #pragma unroll
        for (int rr = 0; rr < 8; ++rr) {
            int lrow = wid * 8 + rr;
            float inv = 1.f / Drow[rr];
            ret[rb + (size_t)lrow * 128 + lane]      = accr[rr][0] * inv;
            ret[rb + (size_t)lrow * 128 + 64 + lane] = accr[rr][1] * inv;
        }
    }
}

// ---------------------------------------------------------------------------
// K7/K8: out BN stats + final
// ---------------------------------------------------------------------------
__global__ __launch_bounds__(256) void k_outstats(const float* __restrict__ ret,
                                                  float* __restrict__ sum,
                                                  float* __restrict__ sq) {
    const int ch = blockIdx.x * 256 + threadIdx.x;
    const int s = ch >> 10, hd = ch & 1023;
    const int h = hd >> 7, d = hd & 127;
    const int row0 = blockIdx.y * 256;
    float sm_ = 0.f, q = 0.f;
    for (int r = 0; r < 256; ++r) {
        int row = row0 + r;
        int b = row >> 10, l = row & 1023;
        float v = ret[((((size_t)s * 4 + b) * 8 + h) * 1024 + l) * 128 + d];
        sm_ += v; q += v * v;
    }
    atomicAdd(&sum[ch], sm_);
    atomicAdd(&sq[ch], q);
}

__global__ __launch_bounds__(256) void k_final(const float* __restrict__ ret,
                                               const float* __restrict__ osum,
                                               const float* __restrict__ osq,
                                               const float* __restrict__ gamma,
                                               const float* __restrict__ beta,
                                               float* __restrict__ out) {
    const int idx = blockIdx.x * 256 + threadIdx.x;
    const int o = idx * 4;
    const int d = o & 127;
    const int h = (o >> 7) & 7;
    const int l = (o >> 10) & 1023;
    const int b = o >> 20;
    const int ch0 = h * 128 + d;
    const int ch1 = 1024 + ch0;
    float4 r0 = *(const float4*)(ret + ((((size_t)0 * 4 + b) * 8 + h) * 1024 + l) * 128 + d);
    float4 r1 = *(const float4*)(ret + ((((size_t)1 * 4 + b) * 8 + h) * 1024 + l) * 128 + d);
    float4 s0 = *(const float4*)(osum + ch0), q0 = *(const float4*)(osq + ch0);
    float4 s1 = *(const float4*)(osum + ch1), q1 = *(const float4*)(osq + ch1);
    float4 g0 = *(const float4*)(gamma + ch0), b0 = *(const float4*)(beta + ch0);
    float4 g1 = *(const float4*)(gamma + ch1), b1 = *(const float4*)(beta + ch1);
    const float inv = 1.f / 4096.f;
    float4 res;
    {
        float m0 = s0.x*inv, v0 = q0.x*inv - m0*m0, a0 = g0.x*rsqrtf(v0+EPSN);
        float m1 = s1.x*inv, v1 = q1.x*inv - m1*m1, a1 = g1.x*rsqrtf(v1+EPSN);
        res.x = a0*(r0.x-m0)+b0.x + a1*(r1.x-m1)+b1.x;
    }
    {
        float m0 = s0.y*inv, v0 = q0.y*inv - m0*m0, a0 = g0.y*rsqrtf(v0+EPSN);
        float m1 = s1.y*inv, v1 = q1.y*inv - m1*m1, a1 = g1.y*rsqrtf(v1+EPSN);
        res.y = a0*(r0.y-m0)+b0.y + a1*(r1.y-m1)+b1.y;
    }
    {
        float m0 = s0.z*inv, v0 = q0.z*inv - m0*m0, a0 = g0.z*rsqrtf(v0+EPSN);
        float m1 = s1.z*inv, v1 = q1.z*inv - m1*m1, a1 = g1.z*rsqrtf(v1+EPSN);
        res.z = a0*(r0.z-m0)+b0.z + a1*(r1.z-m1)+b1.z;
    }
    {
        float m0 = s0.w*inv, v0 = q0.w*inv - m0*m0, a0 = g0.w*rsqrtf(v0+EPSN);
        float m1 = s1.w*inv, v1 = q1.w*inv - m1*m1, a1 = g1.w*rsqrtf(v1+EPSN);
        res.w = a0*(r0.w-m0)+b0.w + a1*(r1.w-m1)+b1.w;
    }
    *(float4*)(out + o) = res;
}

// ---------------------------------------------------------------------------
extern "C" void kernel_launch(void* const* d_in, const int* in_sizes, int n_in,
                              void* d_out, int out_size, void* d_ws, size_t ws_size,
                              hipStream_t stream) {
    const float* x     = (const float*)d_in[0];
    const float* wqkv  = (const float*)d_in[1];
    const float* g_qkv = (const float*)d_in[2];
    const float* b_qkv = (const float*)d_in[3];
    const float* g_sim = (const float*)d_in[4];
    const float* b_sim = (const float*)d_in[5];
    const float* g_out = (const float*)d_in[6];
    const float* b_out = (const float*)d_in[7];
    const float* eq    = (const float*)d_in[8];
    const float* ek    = (const float*)d_in[9];
    const float* ev    = (const float*)d_in[10];
    float* ws  = (float*)d_ws;
    float* out = (float*)d_out;

    hipFuncSetAttribute(reinterpret_cast<const void*>(k_attn<0>),
                        hipFuncAttributeMaxDynamicSharedMemorySize, SMEM0_BYTES);
    hipFuncSetAttribute(reinterpret_cast<const void*>(k_attn<1>),
                        hipFuncAttributeMaxDynamicSharedMemorySize, SMEM1_BYTES);
    hipFuncSetAttribute(reinterpret_cast<const void*>(k_attn2),
                        hipFuncAttributeMaxDynamicSharedMemorySize, SMEMB_BYTES);

    if (ws_size >= NWS_TOTAL_FLOATS * sizeof(float)) {
        // ---------------- NEW path ----------------
        float* qkv    = ws + NWS_QKV;
        unsigned short* Sg  = (unsigned short*)(ws + NWS_S);
        unsigned short* G1g = (unsigned short*)(ws + NWS_G1);
        unsigned short* G2g = (unsigned short*)(ws + NWS_G2);
        float* ret    = ws + NWS_RET;
        float* colsum = ws + NWS_COLSUM;
        float* colsq  = ws + NWS_COLSQ;
        float* simsum = ws + NWS_SIMSUM;
        float* simsq  = ws + NWS_SIMSQ;
        float* outsum = ws + NWS_OUTSUM;
        float* outsq  = ws + NWS_OUTSQ;
        float* qscale = ws + NWS_QSCALE;
        float* qshift = ws + NWS_QSHIFT;
        float* sim_a  = ws + NWS_SIMA;
        float* sim_c  = ws + NWS_SIMC;

        hipMemsetAsync(ws + NWS_STATS, 0, NWS_STATS_N * sizeof(float), stream);

        k_gemm_qkv<<<dim3(32, 64), 256, 0, stream>>>(x, wqkv, qkv);
        k_colstats<<<dim3(8, 16), 256, 0, stream>>>(qkv, colsum, colsq);
        k_fold_qkv<<<dim3(8), 256, 0, stream>>>(colsum, colsq, g_qkv, b_qkv, qscale, qshift);

        k_gemm_bt<0><<<dim3(16, 16, 32), 256, 0, stream>>>(qkv, qscale, qshift, eq, Sg);
        k_gemm_bt<1><<<dim3(8, 512, 1), 256, 0, stream>>>(qkv, qscale, qshift, eq, G1g);
        k_gemm_bt<2><<<dim3(8, 512, 1), 256, 0, stream>>>(qkv, qscale, qshift, ek, G2g);

        k_stats_S<<<dim3(32, 16), 256, 0, stream>>>(Sg, simsum, simsq);
        k_stats_G<1><<<dim3(32, 16), 256, 0, stream>>>(G1g, simsum, simsq);
        k_stats_G<2><<<dim3(32, 16), 256, 0, stream>>>(G2g, simsum, simsq);
        k_fold_sim<<<dim3(1), 32, 0, stream>>>(simsum, simsq, g_sim, b_sim, sim_a, sim_c);

        k_attn2<<<dim3(1024), 256, SMEMB_BYTES, stream>>>(qkv, qscale, qshift,
                                                          Sg, G1g, G2g, ev,
                                                          sim_a, sim_c, ret);

        k_outstats<<<dim3(8, 16), 256, 0, stream>>>(ret, outsum, outsq);
        k_final<<<dim3(4096), 256, 0, stream>>>(ret, outsum, outsq, g_out, b_out, out);
    } else if (ws_size >= WS_TOTAL_FLOATS * sizeof(float)) {
        // ---------------- OLD (round-2) fallback ----------------
        float* qkv    = ws + WS_QKV;
        float* colsum = ws + WS_COLSUM;
        float* colsq  = ws + WS_COLSQ;
        float* simsum = ws + WS_SIMSUM;
        float* simsq  = ws + WS_SIMSQ;
        float* outsum = ws + WS_OUTSUM;
        float* outsq  = ws + WS_OUTSQ;
        float* qscale = ws + WS_QSCALE;
        float* qshift = ws + WS_QSHIFT;
        float* sim_a  = ws + WS_SIMA;
        float* sim_c  = ws + WS_SIMC;
        float* ret    = ws + WS_RET;

        hipMemsetAsync(ws + WS_STATS, 0, WS_STATS_N * sizeof(float), stream);

        k_gemm_qkv<<<dim3(32, 64), 256, 0, stream>>>(x, wqkv, qkv);
        k_colstats<<<dim3(8, 16), 256, 0, stream>>>(qkv, colsum, colsq);
        k_fold_qkv<<<dim3(8), 256, 0, stream>>>(colsum, colsq, g_qkv, b_qkv, qscale, qshift);
        k_attn<0><<<dim3(1024), 256, SMEM0_BYTES, stream>>>(qkv, qscale, qshift, eq, ek, ev,
                                                            sim_a, sim_c, simsum, simsq, ret);
        k_fold_sim<<<dim3(1), 32, 0, stream>>>(simsum, simsq, g_sim, b_sim, sim_a, sim_c);
        k_attn<1><<<dim3(1024), 256, SMEM1_BYTES, stream>>>(qkv, qscale, qshift, eq, ek, ev,
                                                            sim_a, sim_c, simsum, simsq, ret);
        k_outstats<<<dim3(8, 16), 256, 0, stream>>>(ret, outsum, outsq);
        k_final<<<dim3(4096), 256, 0, stream>>>(ret, outsum, outsq, g_out, b_out, out);
    } else {
        hipMemsetAsync(out, 0, (size_t)out_size * sizeof(float), stream);
    }
}

// Round 4
// 746.623 us; speedup vs baseline: 2.9136x; 1.8565x over previous
//
#include <hip/hip_runtime.h>

// ---------------------------------------------------------------------------
// AxialAttention: B=4 L=1024 C=512 DK=512 DV=1024 H=8 DKH=64 DVH=128, R=509
//
// Pipeline:
//   K1 gemm_qkv  : qkv = x @ W_qkv (fp32)
//   K2 colstats / K3 fold_qkv
//   G-GEMMs (bf16 MFMA):  S = Qf@Kf^T per (b,h); G1 = Qf@eq^T; G2 = Kf@ek^T
//   stats_S / stats_G<1,2> / fold_sim
//   k_attn3  : max-free softmax (no shuffles in loop) + MFMA PV + MFMA rel-PV
//   outstats / final
// ---------------------------------------------------------------------------

#define EPSN 1e-5f

// ---- workspace layout (float offsets), same as round 3 (ws >= 201.4MB OK) ----
#define NWS_QKV   0ul
#define NWS_S     8388608ul
#define NWS_G1    25165824ul
#define NWS_G2    33554432ul
#define NWS_RET   41943040ul
#define NWS_STATS 50331648ul
#define NWS_COLSUM (NWS_STATS)
#define NWS_COLSQ  (NWS_STATS + 2048)
#define NWS_SIMSUM (NWS_STATS + 4096)
#define NWS_SIMSQ  (NWS_STATS + 4120)
#define NWS_OUTSUM (NWS_STATS + 4144)
#define NWS_OUTSQ  (NWS_STATS + 6192)
#define NWS_STATS_N 8240ul
#define NWS_FOLD   (NWS_STATS + NWS_STATS_N)
#define NWS_QSCALE (NWS_FOLD)
#define NWS_QSHIFT (NWS_FOLD + 2048)
#define NWS_SIMA   (NWS_FOLD + 4096)
#define NWS_SIMC   (NWS_FOLD + 4120)
#define NWS_TOTAL_FLOATS (NWS_FOLD + 4128ul)     // ~201.4 MB

typedef __attribute__((ext_vector_type(8))) short short8v;
typedef __attribute__((ext_vector_type(4))) float float4v;

__device__ __forceinline__ unsigned short f2bf(float x) {
    union { float f; unsigned int u; } c; c.f = x;
    unsigned int u = c.u + 0x7fffu + ((c.u >> 16) & 1u);   // RNE
    return (unsigned short)(u >> 16);
}
__device__ __forceinline__ float bf2f(unsigned short x) {
    union { unsigned int u; float f; } c; c.u = ((unsigned int)x) << 16;
    return c.f;
}

// ---------------------------------------------------------------------------
// K1: qkv = x[4096,512] @ W[512,2048], fp32 tiled GEMM
// ---------------------------------------------------------------------------
__global__ __launch_bounds__(256) void k_gemm_qkv(const float* __restrict__ x,
                                                  const float* __restrict__ w,
                                                  float* __restrict__ qkv) {
    __shared__ float As[16][68];
    __shared__ float Bs[16][68];
    const int t  = threadIdx.x;
    const int tx = t & 15;
    const int ty = t >> 4;
    const int n0 = blockIdx.x * 64;
    const int r0 = blockIdx.y * 64;
    const int ar = t >> 2, akv = t & 3;
    const int bk = t >> 4, bn = t & 15;
    float acc[4][4];
    #pragma unroll
    for (int i = 0; i < 4; ++i)
        #pragma unroll
        for (int j = 0; j < 4; ++j) acc[i][j] = 0.f;

    for (int k0 = 0; k0 < 512; k0 += 16) {
        __syncthreads();
        float4 av = *(const float4*)(x + (size_t)(r0 + ar) * 512 + k0 + akv * 4);
        As[akv*4+0][ar] = av.x; As[akv*4+1][ar] = av.y;
        As[akv*4+2][ar] = av.z; As[akv*4+3][ar] = av.w;
        float4 bv = *(const float4*)(w + (size_t)(k0 + bk) * 2048 + n0 + bn * 4);
        *(float4*)&Bs[bk][bn*4] = bv;
        __syncthreads();
        #pragma unroll
        for (int kk = 0; kk < 16; ++kk) {
            float4 a = *(const float4*)&As[kk][ty*4];
            float4 b = *(const float4*)&Bs[kk][tx*4];
            acc[0][0] += a.x*b.x; acc[0][1] += a.x*b.y; acc[0][2] += a.x*b.z; acc[0][3] += a.x*b.w;
            acc[1][0] += a.y*b.x; acc[1][1] += a.y*b.y; acc[1][2] += a.y*b.z; acc[1][3] += a.y*b.w;
            acc[2][0] += a.z*b.x; acc[2][1] += a.z*b.y; acc[2][2] += a.z*b.z; acc[2][3] += a.z*b.w;
            acc[3][0] += a.w*b.x; acc[3][1] += a.w*b.y; acc[3][2] += a.w*b.z; acc[3][3] += a.w*b.w;
        }
    }
    #pragma unroll
    for (int i = 0; i < 4; ++i) {
        float4 o = make_float4(acc[i][0], acc[i][1], acc[i][2], acc[i][3]);
        *(float4*)(qkv + (size_t)(r0 + ty*4 + i) * 2048 + n0 + tx*4) = o;
    }
}

// ---------------------------------------------------------------------------
// K2/K3: qkv BN stats + fold
// ---------------------------------------------------------------------------
__global__ __launch_bounds__(256) void k_colstats(const float* __restrict__ src,
                                                  float* __restrict__ sum,
                                                  float* __restrict__ sq) {
    const int ch = blockIdx.x * 256 + threadIdx.x;
    const int r0 = blockIdx.y * 256;
    float s = 0.f, q = 0.f;
    for (int r = 0; r < 256; ++r) {
        float v = src[(size_t)(r0 + r) * 2048 + ch];
        s += v; q += v * v;
    }
    atomicAdd(&sum[ch], s);
    atomicAdd(&sq[ch], q);
}

__global__ __launch_bounds__(256) void k_fold_qkv(const float* __restrict__ sum,
                                                  const float* __restrict__ sq,
                                                  const float* __restrict__ gamma,
                                                  const float* __restrict__ beta,
                                                  float* __restrict__ scale,
                                                  float* __restrict__ shift) {
    const int ch = blockIdx.x * 256 + threadIdx.x;
    float m = sum[ch] * (1.f / 4096.f);
    float v = sq[ch] * (1.f / 4096.f) - m * m;
    float sc = gamma[ch] * rsqrtf(v + EPSN);
    scale[ch] = sc;
    shift[ch] = beta[ch] - sc * m;
}

__global__ void k_fold_sim(const float* __restrict__ simsum,
                           const float* __restrict__ simsq,
                           const float* __restrict__ gamma,
                           const float* __restrict__ beta,
                           float* __restrict__ a_out,
                           float* __restrict__ c_out) {
    __shared__ float part[24];
    const int t = threadIdx.x;
    const float inv = 1.f / (4.f * 1024.f * 1024.f);
    if (t < 24) {
        float m = simsum[t] * inv;
        float v = simsq[t] * inv - m * m;
        float a = gamma[t] * rsqrtf(v + EPSN);
        a_out[t] = a;
        part[t] = beta[t] - a * m;
    }
    __syncthreads();
    if (t < 8) c_out[t] = part[t] + part[8 + t] + part[16 + t];
}

// ---------------------------------------------------------------------------
// bf16 MFMA GEMM  C = fold(A) @ fold(B)^T  (K=64), C written bf16.
// GM=0: S per (b,h) [1024x1024]; GM=1: G1 [32768x512]; GM=2: G2 [32768x512]
// ---------------------------------------------------------------------------
template<int GM>
__global__ __launch_bounds__(256) void k_gemm_bt(
        const float* __restrict__ qkv,
        const float* __restrict__ qscale, const float* __restrict__ qshift,
        const float* __restrict__ emb,
        unsigned short* __restrict__ outp) {
    __shared__ unsigned short Ab[64 * 64];
    __shared__ unsigned short Bb[64 * 64];
    const int t = threadIdx.x;
    const int lane = t & 63, w = t >> 6;
    const int n0 = blockIdx.x * 64;
    const int m0 = blockIdx.y * 64;
    const int z  = blockIdx.z;
    const int sr = t >> 2, sc = (t & 3) * 16;

    // ---- stage A (from qkv, folded) ----
    {
        int grow = m0 + sr;
        const float* src; int ch;
        if (GM == 0) {
            int b = z >> 3, h = z & 7;
            ch = h * 64 + sc;
            src = qkv + ((size_t)(b * 1024 + grow)) * 2048 + ch;
        } else {
            int zz = grow >> 10, l = grow & 1023;
            int b = zz >> 3, h = zz & 7;
            ch = (GM == 2 ? 512 : 0) + h * 64 + sc;
            src = qkv + ((size_t)(b * 1024 + l)) * 2048 + ch;
        }
        unsigned short tmp[16];
        #pragma unroll
        for (int i = 0; i < 4; ++i) {
            float4 v  = *(const float4*)(src + i * 4);
            float4 s4 = *(const float4*)(qscale + ch + i * 4);
            float4 h4 = *(const float4*)(qshift + ch + i * 4);
            tmp[i*4+0] = f2bf(v.x*s4.x+h4.x); tmp[i*4+1] = f2bf(v.y*s4.y+h4.y);
            tmp[i*4+2] = f2bf(v.z*s4.z+h4.z); tmp[i*4+3] = f2bf(v.w*s4.w+h4.w);
        }
        int x0 = (sc * 2) ^ ((sr & 7) << 4);
        int x1 = ((sc * 2) + 16) ^ ((sr & 7) << 4);
        *(uint4*)((char*)Ab + sr * 128 + x0) = *(uint4*)&tmp[0];
        *(uint4*)((char*)Ab + sr * 128 + x1) = *(uint4*)&tmp[8];
    }
    // ---- stage B ----
    {
        unsigned short tmp[16];
        if (GM == 0) {
            int b = z >> 3, h = z & 7;
            int ch = 512 + h * 64 + sc;
            const float* src = qkv + ((size_t)(b * 1024 + n0 + sr)) * 2048 + ch;
            #pragma unroll
            for (int i = 0; i < 4; ++i) {
                float4 v  = *(const float4*)(src + i * 4);
                float4 s4 = *(const float4*)(qscale + ch + i * 4);
                float4 h4 = *(const float4*)(qshift + ch + i * 4);
                tmp[i*4+0] = f2bf(v.x*s4.x+h4.x); tmp[i*4+1] = f2bf(v.y*s4.y+h4.y);
                tmp[i*4+2] = f2bf(v.z*s4.z+h4.z); tmp[i*4+3] = f2bf(v.w*s4.w+h4.w);
            }
        } else {
            int r = n0 + sr;
            if (r < 509) {
                const float* src = emb + (size_t)r * 64 + sc;
                #pragma unroll
                for (int i = 0; i < 4; ++i) {
                    float4 v = *(const float4*)(src + i * 4);
                    tmp[i*4+0] = f2bf(v.x); tmp[i*4+1] = f2bf(v.y);
                    tmp[i*4+2] = f2bf(v.z); tmp[i*4+3] = f2bf(v.w);
                }
            } else {
                #pragma unroll
                for (int i = 0; i < 16; ++i) tmp[i] = 0;
            }
        }
        int x0 = (sc * 2) ^ ((sr & 7) << 4);
        int x1 = ((sc * 2) + 16) ^ ((sr & 7) << 4);
        *(uint4*)((char*)Bb + sr * 128 + x0) = *(uint4*)&tmp[0];
        *(uint4*)((char*)Bb + sr * 128 + x1) = *(uint4*)&tmp[8];
    }
    __syncthreads();

    const int fr = lane & 15, kg = lane >> 4;
    float4v acc[4];
    #pragma unroll
    for (int nt = 0; nt < 4; ++nt) { acc[nt][0]=0.f; acc[nt][1]=0.f; acc[nt][2]=0.f; acc[nt][3]=0.f; }
    #pragma unroll
    for (int ks = 0; ks < 2; ++ks) {
        int arow = w * 16 + fr;
        short8v a = *(short8v*)((char*)Ab + arow * 128 +
                                ((kg * 16 + ks * 64) ^ ((arow & 7) << 4)));
        #pragma unroll
        for (int nt = 0; nt < 4; ++nt) {
            int brow = nt * 16 + fr;
            short8v bf = *(short8v*)((char*)Bb + brow * 128 +
                                     ((kg * 16 + ks * 64) ^ ((brow & 7) << 4)));
            acc[nt] = __builtin_amdgcn_mfma_f32_16x16x32_bf16(a, bf, acc[nt], 0, 0, 0);
        }
    }

    const int crow = (lane >> 4) * 4;
    const int ccol = lane & 15;
    size_t base; int ldc;
    if (GM == 0) { base = (((size_t)z * 1024) + m0 + w * 16) * 1024 + n0; ldc = 1024; }
    else         { base = ((size_t)(m0 + w * 16)) * 512 + n0;             ldc = 512;  }
    #pragma unroll
    for (int nt = 0; nt < 4; ++nt)
        #pragma unroll
        for (int j = 0; j < 4; ++j)
            outp[base + (size_t)(crow + j) * ldc + nt * 16 + ccol] = f2bf(acc[nt][j]);
}

// ---------------------------------------------------------------------------
// sim BN stats
// ---------------------------------------------------------------------------
__global__ __launch_bounds__(256) void k_stats_S(const unsigned short* __restrict__ S,
                                                 float* __restrict__ simsum,
                                                 float* __restrict__ simsq) {
    const int z = blockIdx.x, chunk = blockIdx.y;
    const int h = z & 7;
    const int lane = threadIdx.x & 63;
    size_t base = (size_t)z * 1048576 + (size_t)chunk * 65536;
    float s = 0.f, q = 0.f;
    for (int i = 0; i < 32; ++i) {
        uint4 v = *(const uint4*)(S + base + (size_t)(i * 256 + threadIdx.x) * 8);
        const unsigned short* p = (const unsigned short*)&v;
        #pragma unroll
        for (int j = 0; j < 8; ++j) { float x = bf2f(p[j]); s += x; q += x * x; }
    }
    #pragma unroll
    for (int off = 32; off; off >>= 1) { s += __shfl_xor(s, off); q += __shfl_xor(q, off); }
    if (lane == 0) { atomicAdd(&simsum[h], s); atomicAdd(&simsq[h], q); }
}

template<int WHICH>
__global__ __launch_bounds__(256) void k_stats_G(const unsigned short* __restrict__ G,
                                                 float* __restrict__ simsum,
                                                 float* __restrict__ simsq) {
    const int z = blockIdx.x, lg = blockIdx.y;
    const int h = z & 7;
    const int lane = threadIdx.x & 63, wid = threadIdx.x >> 6;
    float s = 0.f, q = 0.f;
    for (int rr = 0; rr < 16; ++rr) {
        int row = lg * 64 + wid * 16 + rr;
        const unsigned short* g = G + ((size_t)z * 1024 + row) * 512;
        int c0, c508, rlo, rhi;
        if (WHICH == 1) {
            c0 = row - 253 > 0 ? row - 253 : 0;
            c508 = 770 - row > 0 ? 770 - row : 0;
            rlo = 254 - row > 1 ? 254 - row : 1;
            rhi = 1277 - row < 507 ? 1277 - row : 507;
        } else {
            c0 = 770 - row > 0 ? 770 - row : 0;
            c508 = row - 253 > 0 ? row - 253 : 0;
            rlo = row - 769 > 1 ? row - 769 : 1;
            rhi = row + 254 < 507 ? row + 254 : 507;
        }
        #pragma unroll
        for (int i = 0; i < 8; ++i) {
            int r = lane + i * 64;
            float mult = (r == 0) ? (float)c0
                       : (r == 508) ? (float)c508
                       : (r >= rlo && r <= rhi) ? 1.f : 0.f;
            float v = bf2f(g[r]);
            s += mult * v; q += mult * v * v;
        }
    }
    #pragma unroll
    for (int off = 32; off; off >>= 1) { s += __shfl_xor(s, off); q += __shfl_xor(q, off); }
    if (lane == 0) { atomicAdd(&simsum[8 * WHICH + h], s); atomicAdd(&simsq[8 * WHICH + h], q); }
}

// ---------------------------------------------------------------------------
// k_attn3: max-free online softmax + MFMA PV + MFMA rel-PV.
// Block = (b,h,16-row l-tile), 256 thr (4 waves). Grid 2048. LDS 35,840B.
// LDS (ushort idx): Ws[16][72]@0  Wr[16][520]@1152  V[64][132]@9472
// Wave wid owns softmax rows wid*4..+3 and output d-slice [wid*32, wid*32+32).
// ---------------------------------------------------------------------------
#define W3_Ws 0
#define W3_Wr 1152
#define W3_V  9472

__global__ __launch_bounds__(256, 4) void k_attn3(
        const float* __restrict__ qkv,
        const float* __restrict__ qscale, const float* __restrict__ qshift,
        const unsigned short* __restrict__ Sg,
        const unsigned short* __restrict__ G1g,
        const unsigned short* __restrict__ G2g,
        const float* __restrict__ ev,
        const float* __restrict__ sim_a,
        float* __restrict__ ret) {
    __shared__ unsigned short su[17920];
    const int t = threadIdx.x;
    const int lane = t & 63, wid = t >> 6;
    const int blk = blockIdx.x;
    const int lt = blk & 63;
    const int h  = (blk >> 6) & 7;
    const int b  = blk >> 9;
    const int l0 = lt * 16;
    const int z  = b * 8 + h;
    const size_t zS = (size_t)z << 20;
    const size_t zG = (size_t)z * 524288;
    const size_t bbase = (size_t)b * 2097152;
    const float a0c = sim_a[h], a1c = sim_a[8 + h], a2c = sim_a[16 + h];

    // zero Wr (16*520 ushorts = 4160 uints)
    {
        unsigned int* wz = (unsigned int*)(su + W3_Wr);
        #pragma unroll
        for (int i = 0; i < 17; ++i) { int idx = t + i * 256; if (idx < 4160) wz[idx] = 0u; }
    }
    float D[4]  = {0.f, 0.f, 0.f, 0.f};
    float e0[4] = {0.f, 0.f, 0.f, 0.f};
    float e1[4] = {0.f, 0.f, 0.f, 0.f};
    float4v accA0, accA1;
    accA0[0]=0.f; accA0[1]=0.f; accA0[2]=0.f; accA0[3]=0.f;
    accA1[0]=0.f; accA1[1]=0.f; accA1[2]=0.f; accA1[3]=0.f;

    const int vm = t >> 2, vd0 = (t & 3) * 32;       // V staging: row, d-chunk
    const int vch = 1024 + h * 128 + vd0;
    const int fr = lane & 15, kg = lane >> 4;        // MFMA frag ids
    const int dbase = wid * 32;

    for (int mt = 0; mt < 16; ++mt) {
        const int m0 = mt * 64;
        __syncthreads();
        // ---- stage V [64][132] bf16, folded ----
        {
            const float* src = qkv + bbase + (size_t)(m0 + vm) * 2048 + vch;
            const float* scp = qscale + vch;
            const float* shp = qshift + vch;
            unsigned short* dst = su + W3_V + vm * 132 + vd0;
            #pragma unroll
            for (int i = 0; i < 8; ++i) {
                float4 v  = *(const float4*)(src + i * 4);
                float4 s4 = *(const float4*)(scp + i * 4);
                float4 h4 = *(const float4*)(shp + i * 4);
                uint2 pw;
                pw.x = (unsigned int)f2bf(v.x*s4.x+h4.x) | ((unsigned int)f2bf(v.y*s4.y+h4.y) << 16);
                pw.y = (unsigned int)f2bf(v.z*s4.z+h4.z) | ((unsigned int)f2bf(v.w*s4.w+h4.w) << 16);
                *(uint2*)(dst + i * 4) = pw;
            }
        }
        // ---- softmax: 4 owned rows, no cross-lane ops ----
        #pragma unroll
        for (int rr = 0; rr < 4; ++rr) {
            const int lrow = wid * 4 + rr;
            const int l_g = l0 + lrow;
            const int r = m0 + lane - l_g + 254;
            const int rc2 = r < 0 ? 0 : (r > 508 ? 508 : r);
            float sval = bf2f(Sg[zS + (size_t)l_g * 1024 + m0 + lane]);
            float g1   = bf2f(G1g[zG + (size_t)l_g * 512 + rc2]);
            float g2   = bf2f(G2g[zG + (size_t)(m0 + lane) * 512 + rc2]);
            float logit = a0c * sval + a1c * g1 + a2c * g2;   // const cc dropped (cancels)
            float wv = __expf(logit);
            D[rr] += wv;
            bool lo = r <= 0, hi = r >= 508;
            e0[rr] += lo ? wv : 0.f;
            e1[rr] += hi ? wv : 0.f;
            unsigned short hw = f2bf(wv);
            su[W3_Ws + lrow * 72 + lane] = hw;
            if (!lo && !hi) su[W3_Wr + lrow * 520 + r] = hw;
        }
        __syncthreads();
        // ---- PV via MFMA: C[16 l][32 d-slice] += P@V ----
        #pragma unroll
        for (int ks = 0; ks < 2; ++ks) {
            short8v af = *(const short8v*)(su + W3_Ws + fr * 72 + ks * 32 + kg * 8);
            #pragma unroll
            for (int nt = 0; nt < 2; ++nt) {
                const int d = dbase + nt * 16 + fr;
                const unsigned short* vp = su + W3_V + (ks * 32 + kg * 8) * 132 + d;
                short8v bf;
                bf[0] = (short)vp[0 * 132]; bf[1] = (short)vp[1 * 132];
                bf[2] = (short)vp[2 * 132]; bf[3] = (short)vp[3 * 132];
                bf[4] = (short)vp[4 * 132]; bf[5] = (short)vp[5 * 132];
                bf[6] = (short)vp[6 * 132]; bf[7] = (short)vp[7 * 132];
                if (nt == 0) accA0 = __builtin_amdgcn_mfma_f32_16x16x32_bf16(af, bf, accA0, 0, 0, 0);
                else         accA1 = __builtin_amdgcn_mfma_f32_16x16x32_bf16(af, bf, accA1, 0, 0, 0);
            }
        }
    }

    // ---- one-time reductions of D/e0/e1 across lanes ----
    #pragma unroll
    for (int rr = 0; rr < 4; ++rr) {
        #pragma unroll
        for (int off = 32; off; off >>= 1) {
            D[rr]  += __shfl_xor(D[rr], off);
            e0[rr] += __shfl_xor(e0[rr], off);
            e1[rr] += __shfl_xor(e1[rr], off);
        }
    }
    float* Df = (float*)su;                  // reuse Ws region
    __syncthreads();                          // last tile's MFMA reads done
    if (lane == 0) {
        #pragma unroll
        for (int rr = 0; rr < 4; ++rr) {
            int lrow = wid * 4 + rr;
            Df[lrow] = D[rr];
            su[W3_Wr + lrow * 520 + 0]   = f2bf(e0[rr]);
            su[W3_Wr + lrow * 520 + 508] = f2bf(e1[rr]);
        }
    }
    __syncthreads();

    // ---- write retrieved[0] ----
    const int crow = (lane >> 4) * 4, ccol = lane & 15;
    {
        size_t rb = (((size_t)b * 8 + h) * 1024 + l0) * 128;
        #pragma unroll
        for (int j = 0; j < 4; ++j) {
            int row = crow + j;
            float dinv = 1.f / Df[row];
            ret[rb + (size_t)row * 128 + dbase + ccol]      = accA0[j] * dinv;
            ret[rb + (size_t)row * 128 + dbase + 16 + ccol] = accA1[j] * dinv;
        }
    }

    // ---- rel-PV via MFMA: Wr[16][512] @ EV[512][128] ----
    float4v accR0, accR1;
    accR0[0]=0.f; accR0[1]=0.f; accR0[2]=0.f; accR0[3]=0.f;
    accR1[0]=0.f; accR1[1]=0.f; accR1[2]=0.f; accR1[3]=0.f;
    for (int rc = 0; rc < 8; ++rc) {
        __syncthreads();
        // stage EV chunk [64][132] bf16
        {
            int rrow = rc * 64 + vm;
            unsigned short* dst = su + W3_V + vm * 132 + vd0;
            if (rrow < 509) {
                const float* src = ev + (size_t)rrow * 128 + vd0;
                #pragma unroll
                for (int i = 0; i < 8; ++i) {
                    float4 v = *(const float4*)(src + i * 4);
                    uint2 pw;
                    pw.x = (unsigned int)f2bf(v.x) | ((unsigned int)f2bf(v.y) << 16);
                    pw.y = (unsigned int)f2bf(v.z) | ((unsigned int)f2bf(v.w) << 16);
                    *(uint2*)(dst + i * 4) = pw;
                }
            } else {
                uint2 zz; zz.x = 0u; zz.y = 0u;
                #pragma unroll
                for (int i = 0; i < 8; ++i) *(uint2*)(dst + i * 4) = zz;
            }
        }
        __syncthreads();
        #pragma unroll
        for (int ks = 0; ks < 2; ++ks) {
            short8v af = *(const short8v*)(su + W3_Wr + fr * 520 + rc * 64 + ks * 32 + kg * 8);
            #pragma unroll
            for (int nt = 0; nt < 2; ++nt) {
                const int d = dbase + nt * 16 + fr;
                const unsigned short* vp = su + W3_V + (ks * 32 + kg * 8) * 132 + d;
                short8v bf;
                bf[0] = (short)vp[0 * 132]; bf[1] = (short)vp[1 * 132];
                bf[2] = (short)vp[2 * 132]; bf[3] = (short)vp[3 * 132];
                bf[4] = (short)vp[4 * 132]; bf[5] = (short)vp[5 * 132];
                bf[6] = (short)vp[6 * 132]; bf[7] = (short)vp[7 * 132];
                if (nt == 0) accR0 = __builtin_amdgcn_mfma_f32_16x16x32_bf16(af, bf, accR0, 0, 0, 0);
                else         accR1 = __builtin_amdgcn_mfma_f32_16x16x32_bf16(af, bf, accR1, 0, 0, 0);
            }
        }
    }
    {
        size_t rb = ((((size_t)1 * 4 + b) * 8 + h) * 1024 + l0) * 128;
        #pragma unroll
        for (int j = 0; j < 4; ++j) {
            int row = crow + j;
            float dinv = 1.f / Df[row];
            ret[rb + (size_t)row * 128 + dbase + ccol]      = accR0[j] * dinv;
            ret[rb + (size_t)row * 128 + dbase + 16 + ccol] = accR1[j] * dinv;
        }
    }
}

// ---------------------------------------------------------------------------
// out BN stats + final
// ---------------------------------------------------------------------------
__global__ __launch_bounds__(256) void k_outstats(const float* __restrict__ ret,
                                                  float* __restrict__ sum,
                                                  float* __restrict__ sq) {
    const int ch = blockIdx.x * 256 + threadIdx.x;
    const int s = ch >> 10, hd = ch & 1023;
    const int h = hd >> 7, d = hd & 127;
    const int row0 = blockIdx.y * 256;
    float sm_ = 0.f, q = 0.f;
    for (int r = 0; r < 256; ++r) {
        int row = row0 + r;
        int b = row >> 10, l = row & 1023;
        float v = ret[((((size_t)s * 4 + b) * 8 + h) * 1024 + l) * 128 + d];
        sm_ += v; q += v * v;
    }
    atomicAdd(&sum[ch], sm_);
    atomicAdd(&sq[ch], q);
}

__global__ __launch_bounds__(256) void k_final(const float* __restrict__ ret,
                                               const float* __restrict__ osum,
                                               const float* __restrict__ osq,
                                               const float* __restrict__ gamma,
                                               const float* __restrict__ beta,
                                               float* __restrict__ out) {
    const int idx = blockIdx.x * 256 + threadIdx.x;
    const int o = idx * 4;
    const int d = o & 127;
    const int h = (o >> 7) & 7;
    const int l = (o >> 10) & 1023;
    const int b = o >> 20;
    const int ch0 = h * 128 + d;
    const int ch1 = 1024 + ch0;
    float4 r0 = *(const float4*)(ret + ((((size_t)0 * 4 + b) * 8 + h) * 1024 + l) * 128 + d);
    float4 r1 = *(const float4*)(ret + ((((size_t)1 * 4 + b) * 8 + h) * 1024 + l) * 128 + d);
    float4 s0 = *(const float4*)(osum + ch0), q0 = *(const float4*)(osq + ch0);
    float4 s1 = *(const float4*)(osum + ch1), q1 = *(const float4*)(osq + ch1);
    float4 g0 = *(const float4*)(gamma + ch0), b0 = *(const float4*)(beta + ch0);
    float4 g1 = *(const float4*)(gamma + ch1), b1 = *(const float4*)(beta + ch1);
    const float inv = 1.f / 4096.f;
    float4 res;
    {
        float m0 = s0.x*inv, v0 = q0.x*inv - m0*m0, a0 = g0.x*rsqrtf(v0+EPSN);
        float m1 = s1.x*inv, v1 = q1.x*inv - m1*m1, a1 = g1.x*rsqrtf(v1+EPSN);
        res.x = a0*(r0.x-m0)+b0.x + a1*(r1.x-m1)+b1.x;
    }
    {
        float m0 = s0.y*inv, v0 = q0.y*inv - m0*m0, a0 = g0.y*rsqrtf(v0+EPSN);
        float m1 = s1.y*inv, v1 = q1.y*inv - m1*m1, a1 = g1.y*rsqrtf(v1+EPSN);
        res.y = a0*(r0.y-m0)+b0.y + a1*(r1.y-m1)+b1.y;
    }
    {
        float m0 = s0.z*inv, v0 = q0.z*inv - m0*m0, a0 = g0.z*rsqrtf(v0+EPSN);
        float m1 = s1.z*inv, v1 = q1.z*inv - m1*m1, a1 = g1.z*rsqrtf(v1+EPSN);
        res.z = a0*(r0.z-m0)+b0.z + a1*(r1.z-m1)+b1.z;
    }
    {
        float m0 = s0.w*inv, v0 = q0.w*inv - m0*m0, a0 = g0.w*rsqrtf(v0+EPSN);
        float m1 = s1.w*inv, v1 = q1.w*inv - m1*m1, a1 = g1.w*rsqrtf(v1+EPSN);
        res.w = a0*(r0.w-m0)+b0.w + a1*(r1.w-m1)+b1.w;
    }
    *(float4*)(out + o) = res;
}

// ---------------------------------------------------------------------------
extern "C" void kernel_launch(void* const* d_in, const int* in_sizes, int n_in,
                              void* d_out, int out_size, void* d_ws, size_t ws_size,
                              hipStream_t stream) {
    const float* x     = (const float*)d_in[0];
    const float* wqkv  = (const float*)d_in[1];
    const float* g_qkv = (const float*)d_in[2];
    const float* b_qkv = (const float*)d_in[3];
    const float* g_sim = (const float*)d_in[4];
    const float* b_sim = (const float*)d_in[5];
    const float* g_out = (const float*)d_in[6];
    const float* b_out = (const float*)d_in[7];
    const float* eq    = (const float*)d_in[8];
    const float* ek    = (const float*)d_in[9];
    const float* ev    = (const float*)d_in[10];
    float* ws  = (float*)d_ws;
    float* out = (float*)d_out;

    if (ws_size < NWS_TOTAL_FLOATS * sizeof(float)) {
        hipMemsetAsync(out, 0, (size_t)out_size * sizeof(float), stream);
        return;
    }

    float* qkv    = ws + NWS_QKV;
    unsigned short* Sg  = (unsigned short*)(ws + NWS_S);
    unsigned short* G1g = (unsigned short*)(ws + NWS_G1);
    unsigned short* G2g = (unsigned short*)(ws + NWS_G2);
    float* ret    = ws + NWS_RET;
    float* colsum = ws + NWS_COLSUM;
    float* colsq  = ws + NWS_COLSQ;
    float* simsum = ws + NWS_SIMSUM;
    float* simsq  = ws + NWS_SIMSQ;
    float* outsum = ws + NWS_OUTSUM;
    float* outsq  = ws + NWS_OUTSQ;
    float* qscale = ws + NWS_QSCALE;
    float* qshift = ws + NWS_QSHIFT;
    float* sim_a  = ws + NWS_SIMA;
    float* sim_c  = ws + NWS_SIMC;

    hipMemsetAsync(ws + NWS_STATS, 0, NWS_STATS_N * sizeof(float), stream);

    k_gemm_qkv<<<dim3(32, 64), 256, 0, stream>>>(x, wqkv, qkv);
    k_colstats<<<dim3(8, 16), 256, 0, stream>>>(qkv, colsum, colsq);
    k_fold_qkv<<<dim3(8), 256, 0, stream>>>(colsum, colsq, g_qkv, b_qkv, qscale, qshift);

    k_gemm_bt<0><<<dim3(16, 16, 32), 256, 0, stream>>>(qkv, qscale, qshift, eq, Sg);
    k_gemm_bt<1><<<dim3(8, 512, 1), 256, 0, stream>>>(qkv, qscale, qshift, eq, G1g);
    k_gemm_bt<2><<<dim3(8, 512, 1), 256, 0, stream>>>(qkv, qscale, qshift, ek, G2g);

    k_stats_S<<<dim3(32, 16), 256, 0, stream>>>(Sg, simsum, simsq);
    k_stats_G<1><<<dim3(32, 16), 256, 0, stream>>>(G1g, simsum, simsq);
    k_stats_G<2><<<dim3(32, 16), 256, 0, stream>>>(G2g, simsum, simsq);
    k_fold_sim<<<dim3(1), 32, 0, stream>>>(simsum, simsq, g_sim, b_sim, sim_a, sim_c);

    k_attn3<<<dim3(2048), 256, 0, stream>>>(qkv, qscale, qshift, Sg, G1g, G2g, ev,
                                            sim_a, ret);

    k_outstats<<<dim3(8, 16), 256, 0, stream>>>(ret, outsum, outsq);
    k_final<<<dim3(4096), 256, 0, stream>>>(ret, outsum, outsq, g_out, b_out, out);
}

// Round 5
// 656.011 us; speedup vs baseline: 3.3161x; 1.1381x over previous
//
#include <hip/hip_runtime.h>

// ---------------------------------------------------------------------------
// AxialAttention: B=4 L=1024 C=512 DK=512 DV=1024 H=8 DKH=64 DVH=128, R=509
//
// Pipeline:
//   prepx/prepw : x -> xhi/xlo bf16; W -> Wt hi/lo bf16 (transposed)
//   K1' gemm_qkv2 : qkv = x @ W via split-bf16 MFMA (fp32 out)
//   colstats / fold_qkv
//   gemm_bt<0,1,2> (bf16 MFMA) with FUSED sim-BN stats epilogues
//   fold_sim
//   k_logits : S <- a0*S + a1*G1[clamp] + a2*G2[clamp]  (in-place, bf16)
//   prepv/prepev : folded V -> bf16 (in dead G1 region); ev -> bf16 (G2 region)
//   k_attn4 : softmax = 1 coalesced L load + exp; MFMA PV + MFMA rel-PV
//   outstats / final
// ---------------------------------------------------------------------------

#define EPSN 1e-5f

// ---- workspace layout (float offsets); total gate unchanged (~201.4 MB) ----
#define NWS_QKV   0ul
#define NWS_S     8388608ul
#define NWS_G1    25165824ul
#define NWS_G2    33554432ul
#define NWS_RET   41943040ul
#define NWS_STATS 50331648ul
#define NWS_COLSUM (NWS_STATS)
#define NWS_COLSQ  (NWS_STATS + 2048)
#define NWS_SIMSUM (NWS_STATS + 4096)
#define NWS_SIMSQ  (NWS_STATS + 4120)
#define NWS_OUTSUM (NWS_STATS + 4144)
#define NWS_OUTSQ  (NWS_STATS + 6192)
#define NWS_STATS_N 8240ul
#define NWS_FOLD   (NWS_STATS + NWS_STATS_N)
#define NWS_QSCALE (NWS_FOLD)
#define NWS_QSHIFT (NWS_FOLD + 2048)
#define NWS_SIMA   (NWS_FOLD + 4096)
#define NWS_SIMC   (NWS_FOLD + 4120)
#define NWS_TOTAL_FLOATS (NWS_FOLD + 4128ul)

// transient buffers inside dead regions:
//  - xhi/xlo, Wt hi/lo live in RET region (dead until k_attn4; K1' done before)
#define NWS_XHI (NWS_RET)                      // 4096x512 u16 = 1,048,576 f
#define NWS_XLO (NWS_RET + 1048576ul)
#define NWS_WTH (NWS_RET + 2097152ul)          // 2048x512 u16 = 524,288 f
#define NWS_WTL (NWS_RET + 2621440ul)
//  - Vb in G1 region, EVb in G2 region (dead after k_logits)
#define NWS_VB  (NWS_G1)                       // 4096x1024 u16
#define NWS_EVB (NWS_G2)                       // 512x128 u16

typedef __attribute__((ext_vector_type(8))) short short8v;
typedef __attribute__((ext_vector_type(4))) float float4v;

__device__ __forceinline__ unsigned short f2bf(float x) {
    union { float f; unsigned int u; } c; c.f = x;
    unsigned int u = c.u + 0x7fffu + ((c.u >> 16) & 1u);   // RNE
    return (unsigned short)(u >> 16);
}
__device__ __forceinline__ float bf2f(unsigned short x) {
    union { unsigned int u; float f; } c; c.u = ((unsigned int)x) << 16;
    return c.f;
}

// ---------------------------------------------------------------------------
// prepx: x fp32 -> xhi/xlo bf16. 4096*512 = 2,097,152 elems; 8/thread.
// ---------------------------------------------------------------------------
__global__ __launch_bounds__(256) void k_prepx(const float* __restrict__ x,
                                               unsigned short* __restrict__ xh,
                                               unsigned short* __restrict__ xl) {
    const size_t e = ((size_t)blockIdx.x * 256 + threadIdx.x) * 8;
    unsigned short th[8], tl[8];
    #pragma unroll
    for (int i = 0; i < 2; ++i) {
        float4 v = *(const float4*)(x + e + i * 4);
        float vv[4] = {v.x, v.y, v.z, v.w};
        #pragma unroll
        for (int j = 0; j < 4; ++j) {
            unsigned short hi = f2bf(vv[j]);
            th[i*4+j] = hi;
            tl[i*4+j] = f2bf(vv[j] - bf2f(hi));
        }
    }
    *(uint4*)(xh + e) = *(uint4*)th;
    *(uint4*)(xl + e) = *(uint4*)tl;
}

// ---------------------------------------------------------------------------
// prepw: W[512][2048] fp32 -> Wt hi/lo [2048][512] bf16 (transpose via LDS).
// grid (32 n-tiles, 8 k-tiles)
// ---------------------------------------------------------------------------
__global__ __launch_bounds__(256) void k_prepw(const float* __restrict__ w,
                                               unsigned short* __restrict__ wth,
                                               unsigned short* __restrict__ wtl) {
    __shared__ float ws[64][68];
    const int t = threadIdx.x;
    const int n0 = blockIdx.x * 64;
    const int k0 = blockIdx.y * 64;
    #pragma unroll
    for (int i = 0; i < 4; ++i) {
        int row = (t >> 4) + i * 16;             // k-local
        int col = (t & 15) * 4;                  // n-local
        float4 v = *(const float4*)(w + (size_t)(k0 + row) * 2048 + n0 + col);
        ws[row][col] = v.x; ws[row][col+1] = v.y; ws[row][col+2] = v.z; ws[row][col+3] = v.w;
    }
    __syncthreads();
    const int n = t >> 2;                        // out row (n-local)
    const int kc = (t & 3) * 16;                 // k chunk
    unsigned short th[16], tl[16];
    #pragma unroll
    for (int j = 0; j < 16; ++j) {
        float v = ws[kc + j][n];
        unsigned short hi = f2bf(v);
        th[j] = hi; tl[j] = f2bf(v - bf2f(hi));
    }
    size_t base = (size_t)(n0 + n) * 512 + k0 + kc;
    *(uint4*)(wth + base) = *(uint4*)&th[0];
    *(uint4*)(wth + base + 8) = *(uint4*)&th[8];
    *(uint4*)(wtl + base) = *(uint4*)&tl[0];
    *(uint4*)(wtl + base + 8) = *(uint4*)&tl[8];
}

// ---------------------------------------------------------------------------
// K1': qkv = x @ W via split-bf16 MFMA. C = A@B, staged as A rows / Wt rows.
// grid (32 n-tiles, 64 m-tiles), 256 thr. acc += ah*bh + ah*bl + al*bh.
// ---------------------------------------------------------------------------
__global__ __launch_bounds__(256) void k_gemm_qkv2(
        const unsigned short* __restrict__ xh, const unsigned short* __restrict__ xl,
        const unsigned short* __restrict__ wth, const unsigned short* __restrict__ wtl,
        float* __restrict__ qkv) {
    __shared__ unsigned short Ah[4096], Al[4096], Bh[4096], Bl[4096];
    const int t = threadIdx.x;
    const int lane = t & 63, w = t >> 6;
    const int n0 = blockIdx.x * 64;
    const int m0 = blockIdx.y * 64;
    const int sr = t >> 2, sc = (t & 3) * 16;    // stage row, ushort col
    const int x0 = (sc * 2) ^ ((sr & 7) << 4);
    const int x1 = ((sc * 2) + 16) ^ ((sr & 7) << 4);
    const int fr = lane & 15, kg = lane >> 4;

    float4v acc[4];
    #pragma unroll
    for (int nt = 0; nt < 4; ++nt) { acc[nt][0]=0.f; acc[nt][1]=0.f; acc[nt][2]=0.f; acc[nt][3]=0.f; }

    for (int k0 = 0; k0 < 512; k0 += 64) {
        __syncthreads();
        {
            size_t a = (size_t)(m0 + sr) * 512 + k0 + sc;
            uint4 va0 = *(const uint4*)(xh + a), va1 = *(const uint4*)(xh + a + 8);
            *(uint4*)((char*)Ah + sr * 128 + x0) = va0;
            *(uint4*)((char*)Ah + sr * 128 + x1) = va1;
            uint4 vb0 = *(const uint4*)(xl + a), vb1 = *(const uint4*)(xl + a + 8);
            *(uint4*)((char*)Al + sr * 128 + x0) = vb0;
            *(uint4*)((char*)Al + sr * 128 + x1) = vb1;
            size_t bâ = (size_t)(n0 + sr) * 512 + k0 + sc;
            uint4 vc0 = *(const uint4*)(wth + bâ), vc1 = *(const uint4*)(wth + bâ + 8);
            *(uint4*)((char*)Bh + sr * 128 + x0) = vc0;
            *(uint4*)((char*)Bh + sr * 128 + x1) = vc1;
            uint4 vd0 = *(const uint4*)(wtl + bâ), vd1 = *(const uint4*)(wtl + bâ + 8);
            *(uint4*)((char*)Bl + sr * 128 + x0) = vd0;
            *(uint4*)((char*)Bl + sr * 128 + x1) = vd1;
        }
        __syncthreads();
        #pragma unroll
        for (int ks = 0; ks < 2; ++ks) {
            int arow = w * 16 + fr;
            int aoff = (kg * 16 + ks * 64) ^ ((arow & 7) << 4);
            short8v ah = *(short8v*)((char*)Ah + arow * 128 + aoff);
            short8v al = *(short8v*)((char*)Al + arow * 128 + aoff);
            #pragma unroll
            for (int nt = 0; nt < 4; ++nt) {
                int brow = nt * 16 + fr;
                int boff = (kg * 16 + ks * 64) ^ ((brow & 7) << 4);
                short8v bh = *(short8v*)((char*)Bh + brow * 128 + boff);
                short8v bl = *(short8v*)((char*)Bl + brow * 128 + boff);
                acc[nt] = __builtin_amdgcn_mfma_f32_16x16x32_bf16(ah, bh, acc[nt], 0, 0, 0);
                acc[nt] = __builtin_amdgcn_mfma_f32_16x16x32_bf16(ah, bl, acc[nt], 0, 0, 0);
                acc[nt] = __builtin_amdgcn_mfma_f32_16x16x32_bf16(al, bh, acc[nt], 0, 0, 0);
            }
        }
    }
    const int crow = (lane >> 4) * 4, ccol = lane & 15;
    #pragma unroll
    for (int nt = 0; nt < 4; ++nt)
        #pragma unroll
        for (int j = 0; j < 4; ++j)
            qkv[(size_t)(m0 + w * 16 + crow + j) * 2048 + n0 + nt * 16 + ccol] = acc[nt][j];
}

// ---------------------------------------------------------------------------
// K2/K3: qkv BN stats + fold
// ---------------------------------------------------------------------------
__global__ __launch_bounds__(256) void k_colstats(const float* __restrict__ src,
                                                  float* __restrict__ sum,
                                                  float* __restrict__ sq) {
    const int ch = blockIdx.x * 256 + threadIdx.x;
    const int r0 = blockIdx.y * 256;
    float s = 0.f, q = 0.f;
    for (int r = 0; r < 256; ++r) {
        float v = src[(size_t)(r0 + r) * 2048 + ch];
        s += v; q += v * v;
    }
    atomicAdd(&sum[ch], s);
    atomicAdd(&sq[ch], q);
}

__global__ __launch_bounds__(256) void k_fold_qkv(const float* __restrict__ sum,
                                                  const float* __restrict__ sq,
                                                  const float* __restrict__ gamma,
                                                  const float* __restrict__ beta,
                                                  float* __restrict__ scale,
                                                  float* __restrict__ shift) {
    const int ch = blockIdx.x * 256 + threadIdx.x;
    float m = sum[ch] * (1.f / 4096.f);
    float v = sq[ch] * (1.f / 4096.f) - m * m;
    float sc = gamma[ch] * rsqrtf(v + EPSN);
    scale[ch] = sc;
    shift[ch] = beta[ch] - sc * m;
}

__global__ void k_fold_sim(const float* __restrict__ simsum,
                           const float* __restrict__ simsq,
                           const float* __restrict__ gamma,
                           const float* __restrict__ beta,
                           float* __restrict__ a_out,
                           float* __restrict__ c_out) {
    __shared__ float part[24];
    const int t = threadIdx.x;
    const float inv = 1.f / (4.f * 1024.f * 1024.f);
    if (t < 24) {
        float m = simsum[t] * inv;
        float v = simsq[t] * inv - m * m;
        float a = gamma[t] * rsqrtf(v + EPSN);
        a_out[t] = a;
        part[t] = beta[t] - a * m;
    }
    __syncthreads();
    if (t < 8) c_out[t] = part[t] + part[8 + t] + part[16 + t];
}

// ---------------------------------------------------------------------------
// bf16 MFMA GEMM  C = fold(A) @ fold(B)^T  (K=64), C bf16, FUSED sim stats.
// GM=0: S per (b,h); GM=1: G1 [32768x512]; GM=2: G2 [32768x512]
// ---------------------------------------------------------------------------
__device__ __forceinline__ float g_mult(int WHICH, int row, int r) {
    int c0, c508, rlo, rhi;
    if (WHICH == 1) {
        c0 = row - 253 > 0 ? row - 253 : 0;
        c508 = 770 - row > 0 ? 770 - row : 0;
        rlo = 254 - row > 1 ? 254 - row : 1;
        rhi = 1277 - row < 507 ? 1277 - row : 507;
    } else {
        c0 = 770 - row > 0 ? 770 - row : 0;
        c508 = row - 253 > 0 ? row - 253 : 0;
        rlo = row - 769 > 1 ? row - 769 : 1;
        rhi = row + 254 < 507 ? row + 254 : 507;
    }
    return (r == 0) ? (float)c0
         : (r == 508) ? (float)c508
         : (r >= rlo && r <= rhi) ? 1.f : 0.f;
}

template<int GM>
__global__ __launch_bounds__(256) void k_gemm_bt(
        const float* __restrict__ qkv,
        const float* __restrict__ qscale, const float* __restrict__ qshift,
        const float* __restrict__ emb,
        unsigned short* __restrict__ outp,
        float* __restrict__ simsum, float* __restrict__ simsq) {
    __shared__ unsigned short Ab[64 * 64];
    __shared__ unsigned short Bb[64 * 64];
    const int t = threadIdx.x;
    const int lane = t & 63, w = t >> 6;
    const int n0 = blockIdx.x * 64;
    const int m0 = blockIdx.y * 64;
    const int z  = blockIdx.z;
    const int sr = t >> 2, sc = (t & 3) * 16;

    {
        int grow = m0 + sr;
        const float* src; int ch;
        if (GM == 0) {
            int b = z >> 3, h = z & 7;
            ch = h * 64 + sc;
            src = qkv + ((size_t)(b * 1024 + grow)) * 2048 + ch;
        } else {
            int zz = grow >> 10, l = grow & 1023;
            int b = zz >> 3, h = zz & 7;
            ch = (GM == 2 ? 512 : 0) + h * 64 + sc;
            src = qkv + ((size_t)(b * 1024 + l)) * 2048 + ch;
        }
        unsigned short tmp[16];
        #pragma unroll
        for (int i = 0; i < 4; ++i) {
            float4 v  = *(const float4*)(src + i * 4);
            float4 s4 = *(const float4*)(qscale + ch + i * 4);
            float4 h4 = *(const float4*)(qshift + ch + i * 4);
            tmp[i*4+0] = f2bf(v.x*s4.x+h4.x); tmp[i*4+1] = f2bf(v.y*s4.y+h4.y);
            tmp[i*4+2] = f2bf(v.z*s4.z+h4.z); tmp[i*4+3] = f2bf(v.w*s4.w+h4.w);
        }
        int x0 = (sc * 2) ^ ((sr & 7) << 4);
        int x1 = ((sc * 2) + 16) ^ ((sr & 7) << 4);
        *(uint4*)((char*)Ab + sr * 128 + x0) = *(uint4*)&tmp[0];
        *(uint4*)((char*)Ab + sr * 128 + x1) = *(uint4*)&tmp[8];
    }
    {
        unsigned short tmp[16];
        if (GM == 0) {
            int b = z >> 3, h = z & 7;
            int ch = 512 + h * 64 + sc;
            const float* src = qkv + ((size_t)(b * 1024 + n0 + sr)) * 2048 + ch;
            #pragma unroll
            for (int i = 0; i < 4; ++i) {
                float4 v  = *(const float4*)(src + i * 4);
                float4 s4 = *(const float4*)(qscale + ch + i * 4);
                float4 h4 = *(const float4*)(qshift + ch + i * 4);
                tmp[i*4+0] = f2bf(v.x*s4.x+h4.x); tmp[i*4+1] = f2bf(v.y*s4.y+h4.y);
                tmp[i*4+2] = f2bf(v.z*s4.z+h4.z); tmp[i*4+3] = f2bf(v.w*s4.w+h4.w);
            }
        } else {
            int r = n0 + sr;
            if (r < 509) {
                const float* src = emb + (size_t)r * 64 + sc;
                #pragma unroll
                for (int i = 0; i < 4; ++i) {
                    float4 v = *(const float4*)(src + i * 4);
                    tmp[i*4+0] = f2bf(v.x); tmp[i*4+1] = f2bf(v.y);
                    tmp[i*4+2] = f2bf(v.z); tmp[i*4+3] = f2bf(v.w);
                }
            } else {
                #pragma unroll
                for (int i = 0; i < 16; ++i) tmp[i] = 0;
            }
        }
        int x0 = (sc * 2) ^ ((sr & 7) << 4);
        int x1 = ((sc * 2) + 16) ^ ((sr & 7) << 4);
        *(uint4*)((char*)Bb + sr * 128 + x0) = *(uint4*)&tmp[0];
        *(uint4*)((char*)Bb + sr * 128 + x1) = *(uint4*)&tmp[8];
    }
    __syncthreads();

    const int fr = lane & 15, kg = lane >> 4;
    float4v acc[4];
    #pragma unroll
    for (int nt = 0; nt < 4; ++nt) { acc[nt][0]=0.f; acc[nt][1]=0.f; acc[nt][2]=0.f; acc[nt][3]=0.f; }
    #pragma unroll
    for (int ks = 0; ks < 2; ++ks) {
        int arow = w * 16 + fr;
        short8v a = *(short8v*)((char*)Ab + arow * 128 +
                                ((kg * 16 + ks * 64) ^ ((arow & 7) << 4)));
        #pragma unroll
        for (int nt = 0; nt < 4; ++nt) {
            int brow = nt * 16 + fr;
            short8v bf = *(short8v*)((char*)Bb + brow * 128 +
                                     ((kg * 16 + ks * 64) ^ ((brow & 7) << 4)));
            acc[nt] = __builtin_amdgcn_mfma_f32_16x16x32_bf16(a, bf, acc[nt], 0, 0, 0);
        }
    }

    const int crow = (lane >> 4) * 4;
    const int ccol = lane & 15;
    size_t base; int ldc;
    if (GM == 0) { base = (((size_t)z * 1024) + m0 + w * 16) * 1024 + n0; ldc = 1024; }
    else         { base = ((size_t)(m0 + w * 16)) * 512 + n0;             ldc = 512;  }
    #pragma unroll
    for (int nt = 0; nt < 4; ++nt)
        #pragma unroll
        for (int j = 0; j < 4; ++j)
            outp[base + (size_t)(crow + j) * ldc + nt * 16 + ccol] = f2bf(acc[nt][j]);

    // ---- fused sim-BN stats ----
    float s = 0.f, q = 0.f;
    #pragma unroll
    for (int nt = 0; nt < 4; ++nt)
        #pragma unroll
        for (int j = 0; j < 4; ++j) {
            float v = acc[nt][j];
            float mlt;
            if (GM == 0) mlt = 1.f;
            else {
                int row = (m0 + w * 16 + crow + j) & 1023;
                int r = n0 + nt * 16 + ccol;
                mlt = g_mult(GM, row, r);
            }
            s += mlt * v; q += mlt * v * v;
        }
    #pragma unroll
    for (int off = 32; off; off >>= 1) { s += __shfl_xor(s, off); q += __shfl_xor(q, off); }
    __syncthreads();
    float* red = (float*)Ab;
    if (lane == 0) { red[w * 2] = s; red[w * 2 + 1] = q; }
    __syncthreads();
    if (t == 0) {
        float s4 = red[0] + red[2] + red[4] + red[6];
        float q4 = red[1] + red[3] + red[5] + red[7];
        int h = (GM == 0) ? (z & 7) : (((m0 >> 10)) & 7);
        int off0 = (GM == 0) ? 0 : (GM == 1 ? 8 : 16);
        atomicAdd(&simsum[off0 + h], s4);
        atomicAdd(&simsq[off0 + h], q4);
    }
}

// ---------------------------------------------------------------------------
// k_logits: S <- a0*S + a1*G1[l][clamp] + a2*G2[m][clamp]  (bf16, in-place)
// grid (1024 l, 32 z), 256 thr, 4 m per thread.
// ---------------------------------------------------------------------------
__global__ __launch_bounds__(256) void k_logits(
        unsigned short* __restrict__ Sg,
        const unsigned short* __restrict__ G1g,
        const unsigned short* __restrict__ G2g,
        const float* __restrict__ sim_a) {
    const int t = threadIdx.x;
    const int l = blockIdx.x;
    const int z = blockIdx.y;
    const int h = z & 7;
    const float a0c = sim_a[h], a1c = sim_a[8 + h], a2c = sim_a[16 + h];
    const size_t zS = (size_t)z << 20;
    const size_t zG = (size_t)z * 524288;
    const int m = t * 4;
    unsigned short* sp = Sg + zS + (size_t)l * 1024 + m;
    uint2 sv = *(const uint2*)sp;
    const unsigned short* s16 = (const unsigned short*)&sv;
    const unsigned short* g1r = G1g + zG + (size_t)l * 512;
    unsigned short o16[4];
    #pragma unroll
    for (int j = 0; j < 4; ++j) {
        int r = m + j - l + 254;
        int rc = r < 0 ? 0 : (r > 508 ? 508 : r);
        float g1 = bf2f(g1r[rc]);
        float g2 = bf2f(G2g[zG + (size_t)(m + j) * 512 + rc]);
        float lg = a0c * bf2f(s16[j]) + a1c * g1 + a2c * g2;
        o16[j] = f2bf(lg);
    }
    *(uint2*)sp = *(uint2*)o16;
}

// ---------------------------------------------------------------------------
// prepv: Vb[4096][1024] bf16 = fold(qkv V-part). grid (4096).
// ---------------------------------------------------------------------------
__global__ __launch_bounds__(256) void k_prepv(const float* __restrict__ qkv,
                                               const float* __restrict__ qscale,
                                               const float* __restrict__ qshift,
                                               unsigned short* __restrict__ vb) {
    const int row = blockIdx.x;
    const int ch = threadIdx.x * 4;
    float4 v  = *(const float4*)(qkv + (size_t)row * 2048 + 1024 + ch);
    float4 s4 = *(const float4*)(qscale + 1024 + ch);
    float4 h4 = *(const float4*)(qshift + 1024 + ch);
    unsigned short o[4];
    o[0] = f2bf(v.x*s4.x+h4.x); o[1] = f2bf(v.y*s4.y+h4.y);
    o[2] = f2bf(v.z*s4.z+h4.z); o[3] = f2bf(v.w*s4.w+h4.w);
    *(uint2*)(vb + (size_t)row * 1024 + ch) = *(uint2*)o;
}

// prepev: EVb[512][128] bf16, rows 509..511 zero. grid (256).
__global__ __launch_bounds__(256) void k_prepev(const float* __restrict__ ev,
                                                unsigned short* __restrict__ evb) {
    const int e = blockIdx.x * 256 + threadIdx.x;   // 65536 elems
    const int r = e >> 7, d = e & 127;
    evb[e] = (r < 509) ? f2bf(ev[(size_t)r * 128 + d]) : (unsigned short)0;
}

// ---------------------------------------------------------------------------
// k_attn4: softmax from L + MFMA PV + MFMA rel-PV.
// Block = (b,h,16-row l-tile), 256 thr (4 waves). Grid 2048. LDS 35,840B.
// LDS (ushort idx): Ws[16][72]@0  Wr[16][520]@1152  V[64][132]@9472
// ---------------------------------------------------------------------------
#define W3_Ws 0
#define W3_Wr 1152
#define W3_V  9472

__global__ __launch_bounds__(256, 4) void k_attn4(
        const unsigned short* __restrict__ Lg,
        const unsigned short* __restrict__ Vb,
        const unsigned short* __restrict__ EVb,
        float* __restrict__ ret) {
    __shared__ unsigned short su[17920];
    const int t = threadIdx.x;
    const int lane = t & 63, wid = t >> 6;
    const int blk = blockIdx.x;
    const int lt = blk & 63;
    const int h  = (blk >> 6) & 7;
    const int b  = blk >> 9;
    const int l0 = lt * 16;
    const int z  = b * 8 + h;
    const size_t zS = (size_t)z << 20;

    {
        unsigned int* wz = (unsigned int*)(su + W3_Wr);
        #pragma unroll
        for (int i = 0; i < 17; ++i) { int idx = t + i * 256; if (idx < 4160) wz[idx] = 0u; }
    }
    float D[4]  = {0.f, 0.f, 0.f, 0.f};
    float e0[4] = {0.f, 0.f, 0.f, 0.f};
    float e1[4] = {0.f, 0.f, 0.f, 0.f};
    float4v accA0, accA1;
    accA0[0]=0.f; accA0[1]=0.f; accA0[2]=0.f; accA0[3]=0.f;
    accA1[0]=0.f; accA1[1]=0.f; accA1[2]=0.f; accA1[3]=0.f;

    const int vm = t >> 2, vd0 = (t & 3) * 32;       // V staging: row, d-chunk
    const int fr = lane & 15, kg = lane >> 4;
    const int dbase = wid * 32;
    const size_t vbase = ((size_t)b * 1024) * 1024 + h * 128;

    for (int mt = 0; mt < 16; ++mt) {
        const int m0 = mt * 64;
        __syncthreads();
        // ---- T14 split: issue V loads (bf16, prefolded) ----
        uint4 vld[4];
        {
            const unsigned short* src = Vb + vbase + (size_t)(m0 + vm) * 1024 + vd0;
            vld[0] = *(const uint4*)(src);
            vld[1] = *(const uint4*)(src + 8);
            vld[2] = *(const uint4*)(src + 16);
            vld[3] = *(const uint4*)(src + 24);
        }
        // ---- softmax: 1 coalesced L load + exp per element ----
        #pragma unroll
        for (int rr = 0; rr < 4; ++rr) {
            const int lrow = wid * 4 + rr;
            const int l_g = l0 + lrow;
            const int r = m0 + lane - l_g + 254;
            float wv = __expf(bf2f(Lg[zS + (size_t)l_g * 1024 + m0 + lane]));
            D[rr] += wv;
            bool lo = r <= 0, hi = r >= 508;
            e0[rr] += lo ? wv : 0.f;
            e1[rr] += hi ? wv : 0.f;
            unsigned short hw = f2bf(wv);
            su[W3_Ws + lrow * 72 + lane] = hw;
            if (!lo && !hi) su[W3_Wr + lrow * 520 + r] = hw;
        }
        // ---- write V to LDS (pitch 132) ----
        {
            unsigned short* dst = su + W3_V + vm * 132 + vd0;
            const uint2* vsrc = (const uint2*)vld;
            #pragma unroll
            for (int i = 0; i < 8; ++i) *(uint2*)(dst + i * 4) = vsrc[i];
        }
        __syncthreads();
        // ---- PV via MFMA: C[16 l][32 d-slice] += P@V ----
        #pragma unroll
        for (int ks = 0; ks < 2; ++ks) {
            short8v af = *(const short8v*)(su + W3_Ws + fr * 72 + ks * 32 + kg * 8);
            #pragma unroll
            for (int nt = 0; nt < 2; ++nt) {
                const int d = dbase + nt * 16 + fr;
                const unsigned short* vp = su + W3_V + (ks * 32 + kg * 8) * 132 + d;
                short8v bf;
                bf[0] = (short)vp[0 * 132]; bf[1] = (short)vp[1 * 132];
                bf[2] = (short)vp[2 * 132]; bf[3] = (short)vp[3 * 132];
                bf[4] = (short)vp[4 * 132]; bf[5] = (short)vp[5 * 132];
                bf[6] = (short)vp[6 * 132]; bf[7] = (short)vp[7 * 132];
                if (nt == 0) accA0 = __builtin_amdgcn_mfma_f32_16x16x32_bf16(af, bf, accA0, 0, 0, 0);
                else         accA1 = __builtin_amdgcn_mfma_f32_16x16x32_bf16(af, bf, accA1, 0, 0, 0);
            }
        }
    }

    #pragma unroll
    for (int rr = 0; rr < 4; ++rr) {
        #pragma unroll
        for (int off = 32; off; off >>= 1) {
            D[rr]  += __shfl_xor(D[rr], off);
            e0[rr] += __shfl_xor(e0[rr], off);
            e1[rr] += __shfl_xor(e1[rr], off);
        }
    }
    float* Df = (float*)su;
    __syncthreads();
    if (lane == 0) {
        #pragma unroll
        for (int rr = 0; rr < 4; ++rr) {
            int lrow = wid * 4 + rr;
            Df[lrow] = D[rr];
            su[W3_Wr + lrow * 520 + 0]   = f2bf(e0[rr]);
            su[W3_Wr + lrow * 520 + 508] = f2bf(e1[rr]);
        }
    }
    __syncthreads();

    const int crow = (lane >> 4) * 4, ccol = lane & 15;
    {
        size_t rb = (((size_t)b * 8 + h) * 1024 + l0) * 128;
        #pragma unroll
        for (int j = 0; j < 4; ++j) {
            int row = crow + j;
            float dinv = 1.f / Df[row];
            ret[rb + (size_t)row * 128 + dbase + ccol]      = accA0[j] * dinv;
            ret[rb + (size_t)row * 128 + dbase + 16 + ccol] = accA1[j] * dinv;
        }
    }

    // ---- rel-PV via MFMA: Wr[16][512] @ EVb[512][128] ----
    float4v accR0, accR1;
    accR0[0]=0.f; accR0[1]=0.f; accR0[2]=0.f; accR0[3]=0.f;
    accR1[0]=0.f; accR1[1]=0.f; accR1[2]=0.f; accR1[3]=0.f;
    for (int rc = 0; rc < 8; ++rc) {
        __syncthreads();
        {
            const unsigned short* src = EVb + (size_t)(rc * 64 + vm) * 128 + vd0;
            unsigned short* dst = su + W3_V + vm * 132 + vd0;
            uint4 a0 = *(const uint4*)(src);
            uint4 a1 = *(const uint4*)(src + 8);
            uint4 a2 = *(const uint4*)(src + 16);
            uint4 a3 = *(const uint4*)(src + 24);
            uint4 tmp[4] = {a0, a1, a2, a3};
            const uint2* vsrc = (const uint2*)tmp;
            #pragma unroll
            for (int i = 0; i < 8; ++i) *(uint2*)(dst + i * 4) = vsrc[i];
        }
        __syncthreads();
        #pragma unroll
        for (int ks = 0; ks < 2; ++ks) {
            short8v af = *(const short8v*)(su + W3_Wr + fr * 520 + rc * 64 + ks * 32 + kg * 8);
            #pragma unroll
            for (int nt = 0; nt < 2; ++nt) {
                const int d = dbase + nt * 16 + fr;
                const unsigned short* vp = su + W3_V + (ks * 32 + kg * 8) * 132 + d;
                short8v bf;
                bf[0] = (short)vp[0 * 132]; bf[1] = (short)vp[1 * 132];
                bf[2] = (short)vp[2 * 132]; bf[3] = (short)vp[3 * 132];
                bf[4] = (short)vp[4 * 132]; bf[5] = (short)vp[5 * 132];
                bf[6] = (short)vp[6 * 132]; bf[7] = (short)vp[7 * 132];
                if (nt == 0) accR0 = __builtin_amdgcn_mfma_f32_16x16x32_bf16(af, bf, accR0, 0, 0, 0);
                else         accR1 = __builtin_amdgcn_mfma_f32_16x16x32_bf16(af, bf, accR1, 0, 0, 0);
            }
        }
    }
    {
        size_t rb = ((((size_t)1 * 4 + b) * 8 + h) * 1024 + l0) * 128;
        #pragma unroll
        for (int j = 0; j < 4; ++j) {
            int row = crow + j;
            float dinv = 1.f / Df[row];
            ret[rb + (size_t)row * 128 + dbase + ccol]      = accR0[j] * dinv;
            ret[rb + (size_t)row * 128 + dbase + 16 + ccol] = accR1[j] * dinv;
        }
    }
}

// ---------------------------------------------------------------------------
// out BN stats + final
// ---------------------------------------------------------------------------
__global__ __launch_bounds__(256) void k_outstats(const float* __restrict__ ret,
                                                  float* __restrict__ sum,
                                                  float* __restrict__ sq) {
    const int ch = blockIdx.x * 256 + threadIdx.x;
    const int s = ch >> 10, hd = ch & 1023;
    const int h = hd >> 7, d = hd & 127;
    const int row0 = blockIdx.y * 256;
    float sm_ = 0.f, q = 0.f;
    for (int r = 0; r < 256; ++r) {
        int row = row0 + r;
        int b = row >> 10, l = row & 1023;
        float v = ret[((((size_t)s * 4 + b) * 8 + h) * 1024 + l) * 128 + d];
        sm_ += v; q += v * v;
    }
    atomicAdd(&sum[ch], sm_);
    atomicAdd(&sq[ch], q);
}

__global__ __launch_bounds__(256) void k_final(const float* __restrict__ ret,
                                               const float* __restrict__ osum,
                                               const float* __restrict__ osq,
                                               const float* __restrict__ gamma,
                                               const float* __restrict__ beta,
                                               float* __restrict__ out) {
    const int idx = blockIdx.x * 256 + threadIdx.x;
    const int o = idx * 4;
    const int d = o & 127;
    const int h = (o >> 7) & 7;
    const int l = (o >> 10) & 1023;
    const int b = o >> 20;
    const int ch0 = h * 128 + d;
    const int ch1 = 1024 + ch0;
    float4 r0 = *(const float4*)(ret + ((((size_t)0 * 4 + b) * 8 + h) * 1024 + l) * 128 + d);
    float4 r1 = *(const float4*)(ret + ((((size_t)1 * 4 + b) * 8 + h) * 1024 + l) * 128 + d);
    float4 s0 = *(const float4*)(osum + ch0), q0 = *(const float4*)(osq + ch0);
    float4 s1 = *(const float4*)(osum + ch1), q1 = *(const float4*)(osq + ch1);
    float4 g0 = *(const float4*)(gamma + ch0), b0 = *(const float4*)(beta + ch0);
    float4 g1 = *(const float4*)(gamma + ch1), b1 = *(const float4*)(beta + ch1);
    const float inv = 1.f / 4096.f;
    float4 res;
    {
        float m0 = s0.x*inv, v0 = q0.x*inv - m0*m0, a0 = g0.x*rsqrtf(v0+EPSN);
        float m1 = s1.x*inv, v1 = q1.x*inv - m1*m1, a1 = g1.x*rsqrtf(v1+EPSN);
        res.x = a0*(r0.x-m0)+b0.x + a1*(r1.x-m1)+b1.x;
    }
    {
        float m0 = s0.y*inv, v0 = q0.y*inv - m0*m0, a0 = g0.y*rsqrtf(v0+EPSN);
        float m1 = s1.y*inv, v1 = q1.y*inv - m1*m1, a1 = g1.y*rsqrtf(v1+EPSN);
        res.y = a0*(r0.y-m0)+b0.y + a1*(r1.y-m1)+b1.y;
    }
    {
        float m0 = s0.z*inv, v0 = q0.z*inv - m0*m0, a0 = g0.z*rsqrtf(v0+EPSN);
        float m1 = s1.z*inv, v1 = q1.z*inv - m1*m1, a1 = g1.z*rsqrtf(v1+EPSN);
        res.z = a0*(r0.z-m0)+b0.z + a1*(r1.z-m1)+b1.z;
    }
    {
        float m0 = s0.w*inv, v0 = q0.w*inv - m0*m0, a0 = g0.w*rsqrtf(v0+EPSN);
        float m1 = s1.w*inv, v1 = q1.w*inv - m1*m1, a1 = g1.w*rsqrtf(v1+EPSN);
        res.w = a0*(r0.w-m0)+b0.w + a1*(r1.w-m1)+b1.w;
    }
    *(float4*)(out + o) = res;
}

// ---------------------------------------------------------------------------
extern "C" void kernel_launch(void* const* d_in, const int* in_sizes, int n_in,
                              void* d_out, int out_size, void* d_ws, size_t ws_size,
                              hipStream_t stream) {
    const float* x     = (const float*)d_in[0];
    const float* wqkv  = (const float*)d_in[1];
    const float* g_qkv = (const float*)d_in[2];
    const float* b_qkv = (const float*)d_in[3];
    const float* g_sim = (const float*)d_in[4];
    const float* b_sim = (const float*)d_in[5];
    const float* g_out = (const float*)d_in[6];
    const float* b_out = (const float*)d_in[7];
    const float* eq    = (const float*)d_in[8];
    const float* ek    = (const float*)d_in[9];
    const float* ev    = (const float*)d_in[10];
    float* ws  = (float*)d_ws;
    float* out = (float*)d_out;

    if (ws_size < NWS_TOTAL_FLOATS * sizeof(float)) {
        hipMemsetAsync(out, 0, (size_t)out_size * sizeof(float), stream);
        return;
    }

    float* qkv    = ws + NWS_QKV;
    unsigned short* Sg  = (unsigned short*)(ws + NWS_S);
    unsigned short* G1g = (unsigned short*)(ws + NWS_G1);
    unsigned short* G2g = (unsigned short*)(ws + NWS_G2);
    float* ret    = ws + NWS_RET;
    float* colsum = ws + NWS_COLSUM;
    float* colsq  = ws + NWS_COLSQ;
    float* simsum = ws + NWS_SIMSUM;
    float* simsq  = ws + NWS_SIMSQ;
    float* outsum = ws + NWS_OUTSUM;
    float* outsq  = ws + NWS_OUTSQ;
    float* qscale = ws + NWS_QSCALE;
    float* qshift = ws + NWS_QSHIFT;
    float* sim_a  = ws + NWS_SIMA;
    float* sim_c  = ws + NWS_SIMC;
    unsigned short* xh  = (unsigned short*)(ws + NWS_XHI);
    unsigned short* xl  = (unsigned short*)(ws + NWS_XLO);
    unsigned short* wth = (unsigned short*)(ws + NWS_WTH);
    unsigned short* wtl = (unsigned short*)(ws + NWS_WTL);
    unsigned short* vb  = (unsigned short*)(ws + NWS_VB);
    unsigned short* evb = (unsigned short*)(ws + NWS_EVB);
    (void)sim_c;

    hipMemsetAsync(ws + NWS_STATS, 0, NWS_STATS_N * sizeof(float), stream);

    k_prepx<<<dim3(1024), 256, 0, stream>>>(x, xh, xl);
    k_prepw<<<dim3(32, 8), 256, 0, stream>>>(wqkv, wth, wtl);
    k_gemm_qkv2<<<dim3(32, 64), 256, 0, stream>>>(xh, xl, wth, wtl, qkv);

    k_colstats<<<dim3(8, 16), 256, 0, stream>>>(qkv, colsum, colsq);
    k_fold_qkv<<<dim3(8), 256, 0, stream>>>(colsum, colsq, g_qkv, b_qkv, qscale, qshift);

    k_gemm_bt<0><<<dim3(16, 16, 32), 256, 0, stream>>>(qkv, qscale, qshift, eq, Sg, simsum, simsq);
    k_gemm_bt<1><<<dim3(8, 512, 1), 256, 0, stream>>>(qkv, qscale, qshift, eq, G1g, simsum, simsq);
    k_gemm_bt<2><<<dim3(8, 512, 1), 256, 0, stream>>>(qkv, qscale, qshift, ek, G2g, simsum, simsq);

    k_fold_sim<<<dim3(1), 32, 0, stream>>>(simsum, simsq, g_sim, b_sim, sim_a, ws + NWS_SIMC);

    k_logits<<<dim3(1024, 32), 256, 0, stream>>>(Sg, G1g, G2g, sim_a);

    k_prepv<<<dim3(4096), 256, 0, stream>>>(qkv, qscale, qshift, vb);
    k_prepev<<<dim3(256), 256, 0, stream>>>(ev, evb);

    k_attn4<<<dim3(2048), 256, 0, stream>>>(Sg, vb, evb, ret);

    k_outstats<<<dim3(8, 16), 256, 0, stream>>>(ret, outsum, outsq);
    k_final<<<dim3(4096), 256, 0, stream>>>(ret, outsum, outsq, g_out, b_out, out);
}

// Round 6
// 559.149 us; speedup vs baseline: 3.8905x; 1.1732x over previous
//
#include <hip/hip_runtime.h>

// ---------------------------------------------------------------------------
// AxialAttention: B=4 L=1024 C=512 DK=512 DV=1024 H=8 DKH=64 DVH=128, R=509
//
// Pipeline:
//   prepx/prepw : x -> xhi/xlo bf16; W -> Wt hi/lo bf16 (transposed)
//   gemm_qkv2   : qkv = x @ W via split-bf16 MFMA (fp32 out)
//   colstats / fold_qkv
//   prepvT      : folded V -> VbT[z*128+d][1024 m] bf16 (in d_out scratch)
//   prepevT     : ev -> EVbT[128][512] bf16 (in d_out scratch)
//   gemm_bt<0,1,2> (bf16 MFMA) with FUSED sim-BN stats epilogues
//   fold_sim
//   k_attn5     : logits computed in-loop (S/G1 coalesced, G2 via LDS window)
//                 -> exp -> MFMA PV (b128 frags from VbT) + MFMA rel-PV
//   outstats / final
// ---------------------------------------------------------------------------

#define EPSN 1e-5f

// ---- workspace layout (float offsets); gate unchanged (~201.4 MB) ----
#define NWS_QKV   0ul
#define NWS_S     8388608ul
#define NWS_G1    25165824ul
#define NWS_G2    33554432ul
#define NWS_RET   41943040ul
#define NWS_STATS 50331648ul
#define NWS_COLSUM (NWS_STATS)
#define NWS_COLSQ  (NWS_STATS + 2048)
#define NWS_SIMSUM (NWS_STATS + 4096)
#define NWS_SIMSQ  (NWS_STATS + 4120)
#define NWS_OUTSUM (NWS_STATS + 4144)
#define NWS_OUTSQ  (NWS_STATS + 6192)
#define NWS_STATS_N 8240ul
#define NWS_FOLD   (NWS_STATS + NWS_STATS_N)
#define NWS_QSCALE (NWS_FOLD)
#define NWS_QSHIFT (NWS_FOLD + 2048)
#define NWS_SIMA   (NWS_FOLD + 4096)
#define NWS_SIMC   (NWS_FOLD + 4120)
#define NWS_TOTAL_FLOATS (NWS_FOLD + 4128ul)

// transient buffers in dead regions:
//  - xhi/xlo, Wt hi/lo in RET region (dead until attn5 writes ret; qkv2 is early)
#define NWS_XHI (NWS_RET)
#define NWS_XLO (NWS_RET + 1048576ul)
#define NWS_WTH (NWS_RET + 2097152ul)
#define NWS_WTL (NWS_RET + 2621440ul)
//  - VbT (8MB) + EVbT (128KB) live in d_out (dead until k_final overwrites it)

typedef __attribute__((ext_vector_type(8))) short short8v;
typedef __attribute__((ext_vector_type(4))) float float4v;

__device__ __forceinline__ unsigned short f2bf(float x) {
    union { float f; unsigned int u; } c; c.f = x;
    unsigned int u = c.u + 0x7fffu + ((c.u >> 16) & 1u);   // RNE
    return (unsigned short)(u >> 16);
}
__device__ __forceinline__ float bf2f(unsigned short x) {
    union { unsigned int u; float f; } c; c.u = ((unsigned int)x) << 16;
    return c.f;
}

// ---------------------------------------------------------------------------
// prepx: x fp32 -> xhi/xlo bf16
// ---------------------------------------------------------------------------
__global__ __launch_bounds__(256) void k_prepx(const float* __restrict__ x,
                                               unsigned short* __restrict__ xh,
                                               unsigned short* __restrict__ xl) {
    const size_t e = ((size_t)blockIdx.x * 256 + threadIdx.x) * 8;
    unsigned short th[8], tl[8];
    #pragma unroll
    for (int i = 0; i < 2; ++i) {
        float4 v = *(const float4*)(x + e + i * 4);
        float vv[4] = {v.x, v.y, v.z, v.w};
        #pragma unroll
        for (int j = 0; j < 4; ++j) {
            unsigned short hi = f2bf(vv[j]);
            th[i*4+j] = hi;
            tl[i*4+j] = f2bf(vv[j] - bf2f(hi));
        }
    }
    *(uint4*)(xh + e) = *(uint4*)th;
    *(uint4*)(xl + e) = *(uint4*)tl;
}

// ---------------------------------------------------------------------------
// prepw: W[512][2048] -> Wt hi/lo [2048][512] bf16 (transpose via LDS)
// ---------------------------------------------------------------------------
__global__ __launch_bounds__(256) void k_prepw(const float* __restrict__ w,
                                               unsigned short* __restrict__ wth,
                                               unsigned short* __restrict__ wtl) {
    __shared__ float ws[64][68];
    const int t = threadIdx.x;
    const int n0 = blockIdx.x * 64;
    const int k0 = blockIdx.y * 64;
    #pragma unroll
    for (int i = 0; i < 4; ++i) {
        int row = (t >> 4) + i * 16;
        int col = (t & 15) * 4;
        float4 v = *(const float4*)(w + (size_t)(k0 + row) * 2048 + n0 + col);
        ws[row][col] = v.x; ws[row][col+1] = v.y; ws[row][col+2] = v.z; ws[row][col+3] = v.w;
    }
    __syncthreads();
    const int n = t >> 2;
    const int kc = (t & 3) * 16;
    unsigned short th[16], tl[16];
    #pragma unroll
    for (int j = 0; j < 16; ++j) {
        float v = ws[kc + j][n];
        unsigned short hi = f2bf(v);
        th[j] = hi; tl[j] = f2bf(v - bf2f(hi));
    }
    size_t base = (size_t)(n0 + n) * 512 + k0 + kc;
    *(uint4*)(wth + base) = *(uint4*)&th[0];
    *(uint4*)(wth + base + 8) = *(uint4*)&th[8];
    *(uint4*)(wtl + base) = *(uint4*)&tl[0];
    *(uint4*)(wtl + base + 8) = *(uint4*)&tl[8];
}

// ---------------------------------------------------------------------------
// gemm_qkv2: qkv = x @ W via split-bf16 MFMA
// ---------------------------------------------------------------------------
__global__ __launch_bounds__(256) void k_gemm_qkv2(
        const unsigned short* __restrict__ xh, const unsigned short* __restrict__ xl,
        const unsigned short* __restrict__ wth, const unsigned short* __restrict__ wtl,
        float* __restrict__ qkv) {
    __shared__ unsigned short Ah[4096], Al[4096], Bh[4096], Bl[4096];
    const int t = threadIdx.x;
    const int lane = t & 63, w = t >> 6;
    const int n0 = blockIdx.x * 64;
    const int m0 = blockIdx.y * 64;
    const int sr = t >> 2, sc = (t & 3) * 16;
    const int x0 = (sc * 2) ^ ((sr & 7) << 4);
    const int x1 = ((sc * 2) + 16) ^ ((sr & 7) << 4);
    const int fr = lane & 15, kg = lane >> 4;

    float4v acc[4];
    #pragma unroll
    for (int nt = 0; nt < 4; ++nt) { acc[nt][0]=0.f; acc[nt][1]=0.f; acc[nt][2]=0.f; acc[nt][3]=0.f; }

    for (int k0 = 0; k0 < 512; k0 += 64) {
        __syncthreads();
        {
            size_t a = (size_t)(m0 + sr) * 512 + k0 + sc;
            *(uint4*)((char*)Ah + sr * 128 + x0) = *(const uint4*)(xh + a);
            *(uint4*)((char*)Ah + sr * 128 + x1) = *(const uint4*)(xh + a + 8);
            *(uint4*)((char*)Al + sr * 128 + x0) = *(const uint4*)(xl + a);
            *(uint4*)((char*)Al + sr * 128 + x1) = *(const uint4*)(xl + a + 8);
            size_t bb = (size_t)(n0 + sr) * 512 + k0 + sc;
            *(uint4*)((char*)Bh + sr * 128 + x0) = *(const uint4*)(wth + bb);
            *(uint4*)((char*)Bh + sr * 128 + x1) = *(const uint4*)(wth + bb + 8);
            *(uint4*)((char*)Bl + sr * 128 + x0) = *(const uint4*)(wtl + bb);
            *(uint4*)((char*)Bl + sr * 128 + x1) = *(const uint4*)(wtl + bb + 8);
        }
        __syncthreads();
        #pragma unroll
        for (int ks = 0; ks < 2; ++ks) {
            int arow = w * 16 + fr;
            int aoff = (kg * 16 + ks * 64) ^ ((arow & 7) << 4);
            short8v ah = *(short8v*)((char*)Ah + arow * 128 + aoff);
            short8v al = *(short8v*)((char*)Al + arow * 128 + aoff);
            #pragma unroll
            for (int nt = 0; nt < 4; ++nt) {
                int brow = nt * 16 + fr;
                int boff = (kg * 16 + ks * 64) ^ ((brow & 7) << 4);
                short8v bh = *(short8v*)((char*)Bh + brow * 128 + boff);
                short8v bl = *(short8v*)((char*)Bl + brow * 128 + boff);
                acc[nt] = __builtin_amdgcn_mfma_f32_16x16x32_bf16(ah, bh, acc[nt], 0, 0, 0);
                acc[nt] = __builtin_amdgcn_mfma_f32_16x16x32_bf16(ah, bl, acc[nt], 0, 0, 0);
                acc[nt] = __builtin_amdgcn_mfma_f32_16x16x32_bf16(al, bh, acc[nt], 0, 0, 0);
            }
        }
    }
    const int crow = (lane >> 4) * 4, ccol = lane & 15;
    #pragma unroll
    for (int nt = 0; nt < 4; ++nt)
        #pragma unroll
        for (int j = 0; j < 4; ++j)
            qkv[(size_t)(m0 + w * 16 + crow + j) * 2048 + n0 + nt * 16 + ccol] = acc[nt][j];
}

// ---------------------------------------------------------------------------
// qkv BN stats + folds
// ---------------------------------------------------------------------------
__global__ __launch_bounds__(256) void k_colstats(const float* __restrict__ src,
                                                  float* __restrict__ sum,
                                                  float* __restrict__ sq) {
    const int ch = blockIdx.x * 256 + threadIdx.x;
    const int r0 = blockIdx.y * 256;
    float s = 0.f, q = 0.f;
    for (int r = 0; r < 256; ++r) {
        float v = src[(size_t)(r0 + r) * 2048 + ch];
        s += v; q += v * v;
    }
    atomicAdd(&sum[ch], s);
    atomicAdd(&sq[ch], q);
}

__global__ __launch_bounds__(256) void k_fold_qkv(const float* __restrict__ sum,
                                                  const float* __restrict__ sq,
                                                  const float* __restrict__ gamma,
                                                  const float* __restrict__ beta,
                                                  float* __restrict__ scale,
                                                  float* __restrict__ shift) {
    const int ch = blockIdx.x * 256 + threadIdx.x;
    float m = sum[ch] * (1.f / 4096.f);
    float v = sq[ch] * (1.f / 4096.f) - m * m;
    float sc = gamma[ch] * rsqrtf(v + EPSN);
    scale[ch] = sc;
    shift[ch] = beta[ch] - sc * m;
}

__global__ void k_fold_sim(const float* __restrict__ simsum,
                           const float* __restrict__ simsq,
                           const float* __restrict__ gamma,
                           const float* __restrict__ beta,
                           float* __restrict__ a_out,
                           float* __restrict__ c_out) {
    __shared__ float part[24];
    const int t = threadIdx.x;
    const float inv = 1.f / (4.f * 1024.f * 1024.f);
    if (t < 24) {
        float m = simsum[t] * inv;
        float v = simsq[t] * inv - m * m;
        float a = gamma[t] * rsqrtf(v + EPSN);
        a_out[t] = a;
        part[t] = beta[t] - a * m;
    }
    __syncthreads();
    if (t < 8) c_out[t] = part[t] + part[8 + t] + part[16 + t];
}

// ---------------------------------------------------------------------------
// prepvT: VbT[(z*128 + d)*1024 + m] = fold(qkv V-part), transpose via LDS.
// grid (512): blk = z*16 + mtile; 64 m x 128 d per block.
// ---------------------------------------------------------------------------
__global__ __launch_bounds__(256) void k_prepvT(const float* __restrict__ qkv,
                                                const float* __restrict__ qscale,
                                                const float* __restrict__ qshift,
                                                unsigned short* __restrict__ vbT) {
    __shared__ unsigned short tb[64 * 130];
    const int t = threadIdx.x;
    const int blk = blockIdx.x;
    const int z = blk >> 4, mt = blk & 15;
    const int b = z >> 3, h = z & 7;
    const int m0 = mt * 64;
    {
        const int m = t >> 2, dg = (t & 3) * 32;
        const int ch = 1024 + h * 128 + dg;
        const float* src = qkv + ((size_t)(b * 1024 + m0 + m)) * 2048 + ch;
        const float* scp = qscale + ch;
        const float* shp = qshift + ch;
        unsigned short* dst = tb + m * 130 + dg;
        #pragma unroll
        for (int i = 0; i < 8; ++i) {
            float4 v  = *(const float4*)(src + i * 4);
            float4 s4 = *(const float4*)(scp + i * 4);
            float4 h4 = *(const float4*)(shp + i * 4);
            uint2 pw;
            pw.x = (unsigned int)f2bf(v.x*s4.x+h4.x) | ((unsigned int)f2bf(v.y*s4.y+h4.y) << 16);
            pw.y = (unsigned int)f2bf(v.z*s4.z+h4.z) | ((unsigned int)f2bf(v.w*s4.w+h4.w) << 16);
            *(uint2*)(dst + i * 4) = pw;
        }
    }
    __syncthreads();
    {
        const int d = t >> 1, mo = (t & 1) * 32;
        unsigned short o[32];
        #pragma unroll
        for (int j = 0; j < 32; ++j) o[j] = tb[(mo + j) * 130 + d];
        unsigned short* dst = vbT + ((size_t)z * 128 + d) * 1024 + m0 + mo;
        *(uint4*)(dst)      = *(uint4*)&o[0];
        *(uint4*)(dst + 8)  = *(uint4*)&o[8];
        *(uint4*)(dst + 16) = *(uint4*)&o[16];
        *(uint4*)(dst + 24) = *(uint4*)&o[24];
    }
}

// prepevT: EVbT[d*512 + r] = bf16(ev[r][d]), r>=509 zero. grid (8).
__global__ __launch_bounds__(256) void k_prepevT(const float* __restrict__ ev,
                                                 unsigned short* __restrict__ evbT) {
    __shared__ unsigned short tb[64 * 130];
    const int t = threadIdx.x;
    const int r0 = blockIdx.x * 64;
    {
        const int r = t >> 2, dg = (t & 3) * 32;
        const int rr = r0 + r;
        unsigned short* dst = tb + r * 130 + dg;
        if (rr < 509) {
            const float* src = ev + (size_t)rr * 128 + dg;
            #pragma unroll
            for (int i = 0; i < 8; ++i) {
                float4 v = *(const float4*)(src + i * 4);
                uint2 pw;
                pw.x = (unsigned int)f2bf(v.x) | ((unsigned int)f2bf(v.y) << 16);
                pw.y = (unsigned int)f2bf(v.z) | ((unsigned int)f2bf(v.w) << 16);
                *(uint2*)(dst + i * 4) = pw;
            }
        } else {
            uint2 zz; zz.x = 0u; zz.y = 0u;
            #pragma unroll
            for (int i = 0; i < 8; ++i) *(uint2*)(dst + i * 4) = zz;
        }
    }
    __syncthreads();
    {
        const int d = t >> 1, mo = (t & 1) * 32;
        unsigned short o[32];
        #pragma unroll
        for (int j = 0; j < 32; ++j) o[j] = tb[(mo + j) * 130 + d];
        unsigned short* dst = evbT + (size_t)d * 512 + r0 + mo;
        *(uint4*)(dst)      = *(uint4*)&o[0];
        *(uint4*)(dst + 8)  = *(uint4*)&o[8];
        *(uint4*)(dst + 16) = *(uint4*)&o[16];
        *(uint4*)(dst + 24) = *(uint4*)&o[24];
    }
}

// ---------------------------------------------------------------------------
// gemm_bt: C = fold(A) @ fold(B)^T (K=64), C bf16, FUSED sim-BN stats.
// ---------------------------------------------------------------------------
__device__ __forceinline__ float g_mult(int WHICH, int row, int r) {
    int c0, c508, rlo, rhi;
    if (WHICH == 1) {
        c0 = row - 253 > 0 ? row - 253 : 0;
        c508 = 770 - row > 0 ? 770 - row : 0;
        rlo = 254 - row > 1 ? 254 - row : 1;
        rhi = 1277 - row < 507 ? 1277 - row : 507;
    } else {
        c0 = 770 - row > 0 ? 770 - row : 0;
        c508 = row - 253 > 0 ? row - 253 : 0;
        rlo = row - 769 > 1 ? row - 769 : 1;
        rhi = row + 254 < 507 ? row + 254 : 507;
    }
    return (r == 0) ? (float)c0
         : (r == 508) ? (float)c508
         : (r >= rlo && r <= rhi) ? 1.f : 0.f;
}

template<int GM>
__global__ __launch_bounds__(256) void k_gemm_bt(
        const float* __restrict__ qkv,
        const float* __restrict__ qscale, const float* __restrict__ qshift,
        const float* __restrict__ emb,
        unsigned short* __restrict__ outp,
        float* __restrict__ simsum, float* __restrict__ simsq) {
    __shared__ unsigned short Ab[64 * 64];
    __shared__ unsigned short Bb[64 * 64];
    const int t = threadIdx.x;
    const int lane = t & 63, w = t >> 6;
    const int n0 = blockIdx.x * 64;
    const int m0 = blockIdx.y * 64;
    const int z  = blockIdx.z;
    const int sr = t >> 2, sc = (t & 3) * 16;

    {
        int grow = m0 + sr;
        const float* src; int ch;
        if (GM == 0) {
            int b = z >> 3, h = z & 7;
            ch = h * 64 + sc;
            src = qkv + ((size_t)(b * 1024 + grow)) * 2048 + ch;
        } else {
            int zz = grow >> 10, l = grow & 1023;
            int b = zz >> 3, h = zz & 7;
            ch = (GM == 2 ? 512 : 0) + h * 64 + sc;
            src = qkv + ((size_t)(b * 1024 + l)) * 2048 + ch;
        }
        unsigned short tmp[16];
        #pragma unroll
        for (int i = 0; i < 4; ++i) {
            float4 v  = *(const float4*)(src + i * 4);
            float4 s4 = *(const float4*)(qscale + ch + i * 4);
            float4 h4 = *(const float4*)(qshift + ch + i * 4);
            tmp[i*4+0] = f2bf(v.x*s4.x+h4.x); tmp[i*4+1] = f2bf(v.y*s4.y+h4.y);
            tmp[i*4+2] = f2bf(v.z*s4.z+h4.z); tmp[i*4+3] = f2bf(v.w*s4.w+h4.w);
        }
        int x0 = (sc * 2) ^ ((sr & 7) << 4);
        int x1 = ((sc * 2) + 16) ^ ((sr & 7) << 4);
        *(uint4*)((char*)Ab + sr * 128 + x0) = *(uint4*)&tmp[0];
        *(uint4*)((char*)Ab + sr * 128 + x1) = *(uint4*)&tmp[8];
    }
    {
        unsigned short tmp[16];
        if (GM == 0) {
            int b = z >> 3, h = z & 7;
            int ch = 512 + h * 64 + sc;
            const float* src = qkv + ((size_t)(b * 1024 + n0 + sr)) * 2048 + ch;
            #pragma unroll
            for (int i = 0; i < 4; ++i) {
                float4 v  = *(const float4*)(src + i * 4);
                float4 s4 = *(const float4*)(qscale + ch + i * 4);
                float4 h4 = *(const float4*)(qshift + ch + i * 4);
                tmp[i*4+0] = f2bf(v.x*s4.x+h4.x); tmp[i*4+1] = f2bf(v.y*s4.y+h4.y);
                tmp[i*4+2] = f2bf(v.z*s4.z+h4.z); tmp[i*4+3] = f2bf(v.w*s4.w+h4.w);
            }
        } else {
            int r = n0 + sr;
            if (r < 509) {
                const float* src = emb + (size_t)r * 64 + sc;
                #pragma unroll
                for (int i = 0; i < 4; ++i) {
                    float4 v = *(const float4*)(src + i * 4);
                    tmp[i*4+0] = f2bf(v.x); tmp[i*4+1] = f2bf(v.y);
                    tmp[i*4+2] = f2bf(v.z); tmp[i*4+3] = f2bf(v.w);
                }
            } else {
                #pragma unroll
                for (int i = 0; i < 16; ++i) tmp[i] = 0;
            }
        }
        int x0 = (sc * 2) ^ ((sr & 7) << 4);
        int x1 = ((sc * 2) + 16) ^ ((sr & 7) << 4);
        *(uint4*)((char*)Bb + sr * 128 + x0) = *(uint4*)&tmp[0];
        *(uint4*)((char*)Bb + sr * 128 + x1) = *(uint4*)&tmp[8];
    }
    __syncthreads();

    const int fr = lane & 15, kg = lane >> 4;
    float4v acc[4];
    #pragma unroll
    for (int nt = 0; nt < 4; ++nt) { acc[nt][0]=0.f; acc[nt][1]=0.f; acc[nt][2]=0.f; acc[nt][3]=0.f; }
    #pragma unroll
    for (int ks = 0; ks < 2; ++ks) {
        int arow = w * 16 + fr;
        short8v a = *(short8v*)((char*)Ab + arow * 128 +
                                ((kg * 16 + ks * 64) ^ ((arow & 7) << 4)));
        #pragma unroll
        for (int nt = 0; nt < 4; ++nt) {
            int brow = nt * 16 + fr;
            short8v bf = *(short8v*)((char*)Bb + brow * 128 +
                                     ((kg * 16 + ks * 64) ^ ((brow & 7) << 4)));
            acc[nt] = __builtin_amdgcn_mfma_f32_16x16x32_bf16(a, bf, acc[nt], 0, 0, 0);
        }
    }

    const int crow = (lane >> 4) * 4;
    const int ccol = lane & 15;
    size_t base; int ldc;
    if (GM == 0) { base = (((size_t)z * 1024) + m0 + w * 16) * 1024 + n0; ldc = 1024; }
    else         { base = ((size_t)(m0 + w * 16)) * 512 + n0;             ldc = 512;  }
    #pragma unroll
    for (int nt = 0; nt < 4; ++nt)
        #pragma unroll
        for (int j = 0; j < 4; ++j)
            outp[base + (size_t)(crow + j) * ldc + nt * 16 + ccol] = f2bf(acc[nt][j]);

    // fused sim-BN stats
    float s = 0.f, q = 0.f;
    #pragma unroll
    for (int nt = 0; nt < 4; ++nt)
        #pragma unroll
        for (int j = 0; j < 4; ++j) {
            float v = acc[nt][j];
            float mlt;
            if (GM == 0) mlt = 1.f;
            else {
                int row = (m0 + w * 16 + crow + j) & 1023;
                int r = n0 + nt * 16 + ccol;
                mlt = g_mult(GM, row, r);
            }
            s += mlt * v; q += mlt * v * v;
        }
    #pragma unroll
    for (int off = 32; off; off >>= 1) { s += __shfl_xor(s, off); q += __shfl_xor(q, off); }
    __syncthreads();
    float* red = (float*)Ab;
    if (lane == 0) { red[w * 2] = s; red[w * 2 + 1] = q; }
    __syncthreads();
    if (t == 0) {
        float s4 = red[0] + red[2] + red[4] + red[6];
        float q4 = red[1] + red[3] + red[5] + red[7];
        int h = (GM == 0) ? (z & 7) : (((m0 >> 10)) & 7);
        int off0 = (GM == 0) ? 0 : (GM == 1 ? 8 : 16);
        atomicAdd(&simsum[off0 + h], s4);
        atomicAdd(&simsq[off0 + h], q4);
    }
}

// ---------------------------------------------------------------------------
// k_attn5: in-loop logits (S/G1 coalesced + G2 LDS window) -> exp ->
//          MFMA PV (b128 frags from d-major Vt) + MFMA rel-PV.
// Block = (b,h,16-row l-tile), 256 thr (4 waves). Grid 2048. LDS 41,984B.
// LDS (ushort idx): Ws[16][72]@0  Wr[16][520]@2304  Vt[128][72]@10624
//                   G2w[64][18]@19840
// ---------------------------------------------------------------------------
#define A5_Ws 0
#define A5_Wr 2304
#define A5_Vt 10624
#define A5_G2 19840

__global__ __launch_bounds__(256) void k_attn5(
        const unsigned short* __restrict__ Sg,
        const unsigned short* __restrict__ G1g,
        const unsigned short* __restrict__ G2g,
        const unsigned short* __restrict__ VbT,
        const unsigned short* __restrict__ EVbT,
        const float* __restrict__ sim_a,
        float* __restrict__ ret) {
    __shared__ unsigned short su[20992];
    const int t = threadIdx.x;
    const int lane = t & 63, wid = t >> 6;
    const int blk = blockIdx.x;
    const int lt = blk & 63;
    const int h  = (blk >> 6) & 7;
    const int b  = blk >> 9;
    const int l0 = lt * 16;
    const int z  = b * 8 + h;
    const size_t zS = (size_t)z << 20;
    const size_t zG = (size_t)z * 524288;
    const size_t vzb = (size_t)z * 131072;        // z*128*1024
    const float a0c = sim_a[h], a1c = sim_a[8 + h], a2c = sim_a[16 + h];

    {   // zero Wr (16*520 u = 4160 uints)
        unsigned int* wz = (unsigned int*)(su + A5_Wr);
        #pragma unroll
        for (int i = 0; i < 17; ++i) { int idx = t + i * 256; if (idx < 4160) wz[idx] = 0u; }
    }
    float D[4]  = {0.f, 0.f, 0.f, 0.f};
    float e0[4] = {0.f, 0.f, 0.f, 0.f};
    float e1[4] = {0.f, 0.f, 0.f, 0.f};
    float4v accA0, accA1;
    accA0[0]=0.f; accA0[1]=0.f; accA0[2]=0.f; accA0[3]=0.f;
    accA1[0]=0.f; accA1[1]=0.f; accA1[2]=0.f; accA1[3]=0.f;

    const int sd = t >> 1, smo = (t & 1) * 32;    // Vt/EV staging ids
    const int gmm = t >> 2, gj0 = (t & 3) * 4;    // G2w staging ids
    const int fr = lane & 15, kg = lane >> 4;
    const int dbase = wid * 32;

    for (int mt = 0; mt < 16; ++mt) {
        const int m0 = mt * 64;
        __syncthreads();
        {   // stage Vt [128][72] (b128-aligned, ~2-way banks)
            const unsigned short* src = VbT + vzb + (size_t)sd * 1024 + m0 + smo;
            unsigned short* dst = su + A5_Vt + sd * 72 + smo;
            *(uint4*)(dst)      = *(const uint4*)(src);
            *(uint4*)(dst + 8)  = *(const uint4*)(src + 8);
            *(uint4*)(dst + 16) = *(const uint4*)(src + 16);
            *(uint4*)(dst + 24) = *(const uint4*)(src + 24);
        }
        {   // stage G2 diagonal window: G2w[mm][lr] = G2[m0+mm][clamp(rb-lr)]
            const unsigned short* g = G2g + zG + (size_t)(m0 + gmm) * 512;
            int rb = m0 + gmm - l0 + 254;
            #pragma unroll
            for (int j = 0; j < 4; ++j) {
                int lr = gj0 + j;
                int rc = rb - lr; rc = rc < 0 ? 0 : (rc > 508 ? 508 : rc);
                su[A5_G2 + gmm * 18 + lr] = g[rc];
            }
        }
        __syncthreads();
        // in-loop logits + softmax (no cross-lane ops)
        #pragma unroll
        for (int rr = 0; rr < 4; ++rr) {
            const int lrow = wid * 4 + rr;
            const int l_g = l0 + lrow;
            const int r = m0 + lane - l_g + 254;
            const int rc = r < 0 ? 0 : (r > 508 ? 508 : r);
            float sval = bf2f(Sg[zS + (size_t)l_g * 1024 + m0 + lane]);
            float g1   = bf2f(G1g[zG + (size_t)l_g * 512 + rc]);
            float g2   = bf2f(su[A5_G2 + lane * 18 + lrow]);
            float wv = __expf(a0c * sval + a1c * g1 + a2c * g2);
            D[rr] += wv;
            bool lo = r <= 0, hi = r >= 508;
            e0[rr] += lo ? wv : 0.f;
            e1[rr] += hi ? wv : 0.f;
            unsigned short hw = f2bf(wv);
            su[A5_Ws + lrow * 72 + lane] = hw;
            if (!lo && !hi) su[A5_Wr + lrow * 520 + r] = hw;
        }
        __syncthreads();
        // PV MFMA: C[16 l][32 d-slice] += P @ Vt^T
        #pragma unroll
        for (int ks = 0; ks < 2; ++ks) {
            short8v af = *(const short8v*)(su + A5_Ws + fr * 72 + ks * 32 + kg * 8);
            #pragma unroll
            for (int nt = 0; nt < 2; ++nt) {
                const int d = dbase + nt * 16 + fr;
                short8v bf = *(const short8v*)(su + A5_Vt + d * 72 + ks * 32 + kg * 8);
                if (nt == 0) accA0 = __builtin_amdgcn_mfma_f32_16x16x32_bf16(af, bf, accA0, 0, 0, 0);
                else         accA1 = __builtin_amdgcn_mfma_f32_16x16x32_bf16(af, bf, accA1, 0, 0, 0);
            }
        }
    }

    // one-time reductions
    #pragma unroll
    for (int rr = 0; rr < 4; ++rr) {
        #pragma unroll
        for (int off = 32; off; off >>= 1) {
            D[rr]  += __shfl_xor(D[rr], off);
            e0[rr] += __shfl_xor(e0[rr], off);
            e1[rr] += __shfl_xor(e1[rr], off);
        }
    }
    float* Df = (float*)su;                 // reuse Ws region
    __syncthreads();
    if (lane == 0) {
        #pragma unroll
        for (int rr = 0; rr < 4; ++rr) {
            int lrow = wid * 4 + rr;
            Df[lrow] = D[rr];
            su[A5_Wr + lrow * 520 + 0]   = f2bf(e0[rr]);
            su[A5_Wr + lrow * 520 + 508] = f2bf(e1[rr]);
        }
    }
    __syncthreads();

    const int crow = (lane >> 4) * 4, ccol = lane & 15;
    {   // retrieved[0]
        size_t rb = (((size_t)b * 8 + h) * 1024 + l0) * 128;
        #pragma unroll
        for (int j = 0; j < 4; ++j) {
            int row = crow + j;
            float dinv = 1.f / Df[row];
            ret[rb + (size_t)row * 128 + dbase + ccol]      = accA0[j] * dinv;
            ret[rb + (size_t)row * 128 + dbase + 16 + ccol] = accA1[j] * dinv;
        }
    }

    // rel-PV: Wr[16][512] @ EVbT^T
    float4v accR0, accR1;
    accR0[0]=0.f; accR0[1]=0.f; accR0[2]=0.f; accR0[3]=0.f;
    accR1[0]=0.f; accR1[1]=0.f; accR1[2]=0.f; accR1[3]=0.f;
    for (int rc = 0; rc < 8; ++rc) {
        __syncthreads();
        {   // stage EVbT chunk [128][72] cols rc*64..rc*64+63
            const unsigned short* src = EVbT + (size_t)sd * 512 + rc * 64 + smo;
            unsigned short* dst = su + A5_Vt + sd * 72 + smo;
            *(uint4*)(dst)      = *(const uint4*)(src);
            *(uint4*)(dst + 8)  = *(const uint4*)(src + 8);
            *(uint4*)(dst + 16) = *(const uint4*)(src + 16);
            *(uint4*)(dst + 24) = *(const uint4*)(src + 24);
        }
        __syncthreads();
        #pragma unroll
        for (int ks = 0; ks < 2; ++ks) {
            short8v af = *(const short8v*)(su + A5_Wr + fr * 520 + rc * 64 + ks * 32 + kg * 8);
            #pragma unroll
            for (int nt = 0; nt < 2; ++nt) {
                const int d = dbase + nt * 16 + fr;
                short8v bf = *(const short8v*)(su + A5_Vt + d * 72 + ks * 32 + kg * 8);
                if (nt == 0) accR0 = __builtin_amdgcn_mfma_f32_16x16x32_bf16(af, bf, accR0, 0, 0, 0);
                else         accR1 = __builtin_amdgcn_mfma_f32_16x16x32_bf16(af, bf, accR1, 0, 0, 0);
            }
        }
    }
    {
        size_t rb = ((((size_t)1 * 4 + b) * 8 + h) * 1024 + l0) * 128;
        #pragma unroll
        for (int j = 0; j < 4; ++j) {
            int row = crow + j;
            float dinv = 1.f / Df[row];
            ret[rb + (size_t)row * 128 + dbase + ccol]      = accR0[j] * dinv;
            ret[rb + (size_t)row * 128 + dbase + 16 + ccol] = accR1[j] * dinv;
        }
    }
}

// ---------------------------------------------------------------------------
// out BN stats + final
// ---------------------------------------------------------------------------
__global__ __launch_bounds__(256) void k_outstats(const float* __restrict__ ret,
                                                  float* __restrict__ sum,
                                                  float* __restrict__ sq) {
    const int ch = blockIdx.x * 256 + threadIdx.x;
    const int s = ch >> 10, hd = ch & 1023;
    const int h = hd >> 7, d = hd & 127;
    const int row0 = blockIdx.y * 256;
    float sm_ = 0.f, q = 0.f;
    for (int r = 0; r < 256; ++r) {
        int row = row0 + r;
        int b = row >> 10, l = row & 1023;
        float v = ret[((((size_t)s * 4 + b) * 8 + h) * 1024 + l) * 128 + d];
        sm_ += v; q += v * v;
    }
    atomicAdd(&sum[ch], sm_);
    atomicAdd(&sq[ch], q);
}

__global__ __launch_bounds__(256) void k_final(const float* __restrict__ ret,
                                               const float* __restrict__ osum,
                                               const float* __restrict__ osq,
                                               const float* __restrict__ gamma,
                                               const float* __restrict__ beta,
                                               float* __restrict__ out) {
    const int idx = blockIdx.x * 256 + threadIdx.x;
    const int o = idx * 4;
    const int d = o & 127;
    const int h = (o >> 7) & 7;
    const int l = (o >> 10) & 1023;
    const int b = o >> 20;
    const int ch0 = h * 128 + d;
    const int ch1 = 1024 + ch0;
    float4 r0 = *(const float4*)(ret + ((((size_t)0 * 4 + b) * 8 + h) * 1024 + l) * 128 + d);
    float4 r1 = *(const float4*)(ret + ((((size_t)1 * 4 + b) * 8 + h) * 1024 + l) * 128 + d);
    float4 s0 = *(const float4*)(osum + ch0), q0 = *(const float4*)(osq + ch0);
    float4 s1 = *(const float4*)(osum + ch1), q1 = *(const float4*)(osq + ch1);
    float4 g0 = *(const float4*)(gamma + ch0), b0 = *(const float4*)(beta + ch0);
    float4 g1 = *(const float4*)(gamma + ch1), b1 = *(const float4*)(beta + ch1);
    const float inv = 1.f / 4096.f;
    float4 res;
    {
        float m0 = s0.x*inv, v0 = q0.x*inv - m0*m0, a0 = g0.x*rsqrtf(v0+EPSN);
        float m1 = s1.x*inv, v1 = q1.x*inv - m1*m1, a1 = g1.x*rsqrtf(v1+EPSN);
        res.x = a0*(r0.x-m0)+b0.x + a1*(r1.x-m1)+b1.x;
    }
    {
        float m0 = s0.y*inv, v0 = q0.y*inv - m0*m0, a0 = g0.y*rsqrtf(v0+EPSN);
        float m1 = s1.y*inv, v1 = q1.y*inv - m1*m1, a1 = g1.y*rsqrtf(v1+EPSN);
        res.y = a0*(r0.y-m0)+b0.y + a1*(r1.y-m1)+b1.y;
    }
    {
        float m0 = s0.z*inv, v0 = q0.z*inv - m0*m0, a0 = g0.z*rsqrtf(v0+EPSN);
        float m1 = s1.z*inv, v1 = q1.z*inv - m1*m1, a1 = g1.z*rsqrtf(v1+EPSN);
        res.z = a0*(r0.z-m0)+b0.z + a1*(r1.z-m1)+b1.z;
    }
    {
        float m0 = s0.w*inv, v0 = q0.w*inv - m0*m0, a0 = g0.w*rsqrtf(v0+EPSN);
        float m1 = s1.w*inv, v1 = q1.w*inv - m1*m1, a1 = g1.w*rsqrtf(v1+EPSN);
        res.w = a0*(r0.w-m0)+b0.w + a1*(r1.w-m1)+b1.w;
    }
    *(float4*)(out + o) = res;
}

// ---------------------------------------------------------------------------
extern "C" void kernel_launch(void* const* d_in, const int* in_sizes, int n_in,
                              void* d_out, int out_size, void* d_ws, size_t ws_size,
                              hipStream_t stream) {
    const float* x     = (const float*)d_in[0];
    const float* wqkv  = (const float*)d_in[1];
    const float* g_qkv = (const float*)d_in[2];
    const float* b_qkv = (const float*)d_in[3];
    const float* g_sim = (const float*)d_in[4];
    const float* b_sim = (const float*)d_in[5];
    const float* g_out = (const float*)d_in[6];
    const float* b_out = (const float*)d_in[7];
    const float* eq    = (const float*)d_in[8];
    const float* ek    = (const float*)d_in[9];
    const float* ev    = (const float*)d_in[10];
    float* ws  = (float*)d_ws;
    float* out = (float*)d_out;

    if (ws_size < NWS_TOTAL_FLOATS * sizeof(float)) {
        hipMemsetAsync(out, 0, (size_t)out_size * sizeof(float), stream);
        return;
    }

    float* qkv    = ws + NWS_QKV;
    unsigned short* Sg  = (unsigned short*)(ws + NWS_S);
    unsigned short* G1g = (unsigned short*)(ws + NWS_G1);
    unsigned short* G2g = (unsigned short*)(ws + NWS_G2);
    float* ret    = ws + NWS_RET;
    float* colsum = ws + NWS_COLSUM;
    float* colsq  = ws + NWS_COLSQ;
    float* simsum = ws + NWS_SIMSUM;
    float* simsq  = ws + NWS_SIMSQ;
    float* outsum = ws + NWS_OUTSUM;
    float* outsq  = ws + NWS_OUTSQ;
    float* qscale = ws + NWS_QSCALE;
    float* qshift = ws + NWS_QSHIFT;
    float* sim_a  = ws + NWS_SIMA;
    unsigned short* xh  = (unsigned short*)(ws + NWS_XHI);
    unsigned short* xl  = (unsigned short*)(ws + NWS_XLO);
    unsigned short* wth = (unsigned short*)(ws + NWS_WTH);
    unsigned short* wtl = (unsigned short*)(ws + NWS_WTL);
    // VbT (8MB) + EVbT (128KB) in d_out scratch (dead until k_final writes it)
    unsigned short* vbT  = (unsigned short*)out;
    unsigned short* evbT = (unsigned short*)(out + 2097152);

    hipMemsetAsync(ws + NWS_STATS, 0, NWS_STATS_N * sizeof(float), stream);

    k_prepx<<<dim3(1024), 256, 0, stream>>>(x, xh, xl);
    k_prepw<<<dim3(32, 8), 256, 0, stream>>>(wqkv, wth, wtl);
    k_gemm_qkv2<<<dim3(32, 64), 256, 0, stream>>>(xh, xl, wth, wtl, qkv);

    k_colstats<<<dim3(8, 16), 256, 0, stream>>>(qkv, colsum, colsq);
    k_fold_qkv<<<dim3(8), 256, 0, stream>>>(colsum, colsq, g_qkv, b_qkv, qscale, qshift);

    k_prepvT<<<dim3(512), 256, 0, stream>>>(qkv, qscale, qshift, vbT);
    k_prepevT<<<dim3(8), 256, 0, stream>>>(ev, evbT);

    k_gemm_bt<0><<<dim3(16, 16, 32), 256, 0, stream>>>(qkv, qscale, qshift, eq, Sg, simsum, simsq);
    k_gemm_bt<1><<<dim3(8, 512, 1), 256, 0, stream>>>(qkv, qscale, qshift, eq, G1g, simsum, simsq);
    k_gemm_bt<2><<<dim3(8, 512, 1), 256, 0, stream>>>(qkv, qscale, qshift, ek, G2g, simsum, simsq);

    k_fold_sim<<<dim3(1), 32, 0, stream>>>(simsum, simsq, g_sim, b_sim, sim_a, ws + NWS_SIMC);

    k_attn5<<<dim3(2048), 256, 0, stream>>>(Sg, G1g, G2g, vbT, evbT, sim_a, ret);

    k_outstats<<<dim3(8, 16), 256, 0, stream>>>(ret, outsum, outsq);
    k_final<<<dim3(4096), 256, 0, stream>>>(ret, outsum, outsq, g_out, b_out, out);
}